// Round 5
// baseline (7332.677 us; speedup 1.0000x reference)
//
#include <hip/hip_runtime.h>

#define NHEAD 16
#define DHEAD 64
#define XLEN 1024
#define MEMLEN 1024
#define BATCH 4
#define TOT 2048
#define DFF 4096
#define DM 1024

typedef __attribute__((ext_vector_type(8))) short bf16x8;
typedef __attribute__((ext_vector_type(4))) float f32x4;
typedef __attribute__((ext_vector_type(8))) _Float16 f16x8;
typedef __attribute__((ext_vector_type(4))) _Float16 f16x4;

#define MFB(A, B, C) __builtin_amdgcn_mfma_f32_16x16x32_bf16(A, B, C, 0, 0, 0)
#define MFH(A, B, C) __builtin_amdgcn_mfma_f32_16x16x32_f16(A, B, C, 0, 0, 0)

__device__ __forceinline__ unsigned short bf16rn(float x) {
  union { float f; unsigned u; } c{x};
  unsigned r = c.u + 0x7fffu + ((c.u >> 16) & 1u);
  return (unsigned short)(r >> 16);
}
__device__ __forceinline__ float bf16tof(unsigned short h) {
  union { unsigned u; float f; } c{(unsigned)h << 16};
  return c.f;
}

#define GLOAD_LDS16(gp, lp)                                                    \
  __builtin_amdgcn_global_load_lds(                                            \
      (const __attribute__((address_space(1))) unsigned int*)(gp),             \
      (__attribute__((address_space(3))) unsigned int*)(lp), 16, 0, 0)

// ---------------- elementwise split: fp32 -> bf16 hi + bf16 lo --------------
__global__ __launch_bounds__(256) void split2_k(
    const float* __restrict__ s0, const float* __restrict__ s1, int splitElems,
    unsigned short* __restrict__ oh, unsigned short* __restrict__ ol)
{
  int i4 = (blockIdx.x * 256 + threadIdx.x) * 4;
  const float* src = (i4 < splitElems) ? (s0 + i4) : (s1 + (i4 - splitElems));
  float4 v = *(const float4*)src;
  ushort4 h, l;
  h.x = bf16rn(v.x); l.x = bf16rn(v.x - bf16tof(h.x));
  h.y = bf16rn(v.y); l.y = bf16rn(v.y - bf16tof(h.y));
  h.z = bf16rn(v.z); l.z = bf16rn(v.z - bf16tof(h.z));
  h.w = bf16rn(v.w); l.w = bf16rn(v.w - bf16tof(h.w));
  *(ushort4*)(oh + i4) = h;
  *(ushort4*)(ol + i4) = l;
}

// ------------- transpose + split: W[K][N] fp32 -> Wt hi/lo [N][K] bf16 ------
__global__ __launch_bounds__(256) void tsplit_k(
    const float* __restrict__ W, int K, int N,
    unsigned short* __restrict__ oh, unsigned short* __restrict__ ol)
{
  __shared__ float tile[64][65];
  const int t = threadIdx.x;
  const int bk = blockIdx.x * 64, bn = blockIdx.y * 64;
#pragma unroll
  for (int r = 0; r < 4; ++r) {
    int lr = r * 16 + (t >> 4), lc = (t & 15) * 4;
    *(float4*)&tile[lr][lc] = *(const float4*)&W[(size_t)(bk + lr) * N + bn + lc];
  }
  __syncthreads();
  const int n = t >> 2, kq = t & 3;
  unsigned short* ph = oh + (size_t)(bn + n) * K + bk + kq * 16;
  unsigned short* pl = ol + (size_t)(bn + n) * K + bk + kq * 16;
#pragma unroll
  for (int c = 0; c < 4; ++c) {
    ushort4 h, l;
    float v0 = tile[kq * 16 + c * 4 + 0][n];
    float v1 = tile[kq * 16 + c * 4 + 1][n];
    float v2 = tile[kq * 16 + c * 4 + 2][n];
    float v3 = tile[kq * 16 + c * 4 + 3][n];
    h.x = bf16rn(v0); l.x = bf16rn(v0 - bf16tof(h.x));
    h.y = bf16rn(v1); l.y = bf16rn(v1 - bf16tof(h.y));
    h.z = bf16rn(v2); l.z = bf16rn(v2 - bf16tof(h.z));
    h.w = bf16rn(v3); l.w = bf16rn(v3 - bf16tof(h.w));
    *(ushort4*)(ph + c * 4) = h;
    *(ushort4*)(pl + c * 4) = l;
  }
}

// ---------------- MFMA GEMM: 128x128 tile, 3-term Markidis ------------------
template<int MODE>
__global__ __launch_bounds__(256) void gemm_k(
    const unsigned short* __restrict__ Ah, const unsigned short* __restrict__ Al,
    const unsigned short* __restrict__ Bh, const unsigned short* __restrict__ Bl,
    int N, int K,
    const float* __restrict__ e0, const float* __restrict__ e1,
    float* __restrict__ o0,
    unsigned short* __restrict__ p0, unsigned short* __restrict__ p1,
    unsigned short* __restrict__ p2, unsigned short* __restrict__ p3)
{
  __shared__ unsigned short lds[4][4096];  // Ah,Al,Bh,Bl: 128 rows x 32 bf16
  const int t = threadIdx.x;
  const int wave = t >> 6, lane = t & 63;
  const int wm = wave >> 1, wn = wave & 1;
  const int m0 = blockIdx.y * 128, n0 = blockIdx.x * 128;

  const unsigned short* gp[2][4];
  unsigned short* lp[2][4];
#pragma unroll
  for (int i = 0; i < 2; ++i) {
    int s = i * 256 + t, row = s >> 2, sl = s & 3;
    int csw = (sl ^ (row & 3)) * 8;
    gp[i][0] = Ah + (size_t)(m0 + row) * K + csw;
    gp[i][1] = Al + (size_t)(m0 + row) * K + csw;
    gp[i][2] = Bh + (size_t)(n0 + row) * K + csw;
    gp[i][3] = Bl + (size_t)(n0 + row) * K + csw;
#pragma unroll
    for (int a = 0; a < 4; ++a) lp[i][a] = &lds[a][s * 8];
  }

  f32x4 acc[4][4] = {};
  const int kg = lane >> 4, r15 = lane & 15;

  for (int k0 = 0; k0 < K; k0 += 32) {
#pragma unroll
    for (int i = 0; i < 2; ++i)
#pragma unroll
      for (int a = 0; a < 4; ++a) GLOAD_LDS16(gp[i][a] + k0, lp[i][a]);
    __syncthreads();

    bf16x8 afh[4], afl[4], bfh[4], bfl[4];
#pragma unroll
    for (int f = 0; f < 4; ++f) {
      int rowA = wm * 64 + f * 16 + r15;
      int ia = (rowA * 4 + (kg ^ (rowA & 3))) * 8;
      afh[f] = *(const bf16x8*)&lds[0][ia];
      afl[f] = *(const bf16x8*)&lds[1][ia];
      int rowB = wn * 64 + f * 16 + r15;
      int ib = (rowB * 4 + (kg ^ (rowB & 3))) * 8;
      bfh[f] = *(const bf16x8*)&lds[2][ib];
      bfl[f] = *(const bf16x8*)&lds[3][ib];
    }
#pragma unroll
    for (int i = 0; i < 4; ++i)
#pragma unroll
      for (int j = 0; j < 4; ++j) {
        acc[i][j] = MFB(afh[i], bfh[j], acc[i][j]);
        acc[i][j] = MFB(afh[i], bfl[j], acc[i][j]);
        acc[i][j] = MFB(afl[i], bfh[j], acc[i][j]);
      }
    __syncthreads();
  }

  // epilogue: C/D layout col = lane&15, row = (lane>>4)*4 + reg
#pragma unroll
  for (int i = 0; i < 4; ++i)
#pragma unroll
    for (int j = 0; j < 4; ++j)
#pragma unroll
      for (int r = 0; r < 4; ++r) {
        int m = m0 + wm * 64 + i * 16 + kg * 4 + r;
        int nn = n0 + wn * 64 + j * 16 + r15;
        float v = acc[i][j][r];
        if (MODE == 0) {           // c@Wkv -> Kh/Kl [B,N,T,64], VT f16 [B,N,64,T]
          int tt = m >> 2, bb = m & 3;
          if (nn < 1024) {
            int hn = nn >> 6, d = nn & 63;
            size_t idx = ((size_t)(bb * 16 + hn) * 2048 + tt) * 64 + d;
            unsigned short hi = bf16rn(v);
            p0[idx] = hi; p1[idx] = bf16rn(v - bf16tof(hi));
          } else {
            int c2 = nn - 1024, hn = c2 >> 6, d = c2 & 63;
            union { _Float16 h; unsigned short u; } cv; cv.h = (_Float16)v;
            p2[((size_t)(bb * 16 + hn) * 64 + d) * 2048 + tt] = cv.u;
          }
        } else if (MODE == 1) {    // x@Wq + biases -> Quh/Qul/Qvh/Qvl [B,N,I,64]
          int i2 = m >> 2, bb = m & 3;
          int hn = nn >> 6, d = nn & 63;
          size_t idx = ((size_t)(bb * 16 + hn) * 1024 + i2) * 64 + d;
          float vu = v + e0[nn], vv = v + e1[nn];
          unsigned short h0 = bf16rn(vu);
          p0[idx] = h0; p1[idx] = bf16rn(vu - bf16tof(h0));
          unsigned short h1 = bf16rn(vv);
          p2[idx] = h1; p3[idx] = bf16rn(vv - bf16tof(h1));
        } else if (MODE == 2) {    // pos@Wrel -> Rh/Rl [B,N,T,64]
          int tt = m >> 2, bb = m & 3;
          int hn = nn >> 6, d = nn & 63;
          size_t idx = ((size_t)(bb * 16 + hn) * 2048 + tt) * 64 + d;
          unsigned short hi = bf16rn(v);
          p0[idx] = hi; p1[idx] = bf16rn(v - bf16tof(hi));
        } else if (MODE == 3) {    // vec@Wo + x -> t1 (fp32)
          o0[(size_t)m * N + nn] = v + e0[(size_t)m * N + nn];
        } else if (MODE == 4) {    // relu(h@W1 + b1) -> ffp hi/lo bf16
          float v2 = fmaxf(v + e0[nn], 0.f);
          unsigned short hh = bf16rn(v2);
          p0[(size_t)m * N + nn] = hh;
          p1[(size_t)m * N + nn] = bf16rn(v2 - bf16tof(hh));
        } else if (MODE == 5) {    // ff@W2 + b2 + h -> t2 (fp32)
          o0[(size_t)m * N + nn] = v + e0[nn] + e1[(size_t)m * N + nn];
        }
      }
}

// ---------------- MFMA attention ----------------
// block = (16 q-rows, b, 8-head group); 8 waves; swapped-operand S^T so each
// lane holds one q-row's 64 scores in regs. D (rel-pos) via MFMA into f16 LDS
// window; exact per-row fp32 softmax; PV via f16 MFMA.
__global__ __launch_bounds__(512, 4) void attn_k(
    const unsigned short* __restrict__ Kh, const unsigned short* __restrict__ Kl,
    const unsigned short* __restrict__ Rh, const unsigned short* __restrict__ Rl,
    const unsigned short* __restrict__ Quh, const unsigned short* __restrict__ Qul,
    const unsigned short* __restrict__ Qvh, const unsigned short* __restrict__ Qvl,
    const _Float16* __restrict__ VT,
    float* __restrict__ vec, float* __restrict__ attnacc)
{
  __shared__ _Float16 Dl[16][2072];            // D window, then normalized P
  __shared__ unsigned short qs[4][8][16][8];   // Q^T frags: arr, dchunk, i, e
  __shared__ float red[2][8][16];
  const int t = threadIdx.x, wave = t >> 6, lane = t & 63;
  const int g = lane >> 4, i15 = lane & 15;
  const int i0 = blockIdx.x * 16, b = blockIdx.y;
  const int jr0 = 1008 - i0;
  const int NS = (2048 - jr0) >> 4;
  const int jb = wave * 256;

  for (int hh = 0; hh < 8; ++hh) {
    const int n = blockIdx.z * 8 + hh;
    const size_t bn = (size_t)(b * 16 + n);

    {  // stage Q^T tiles (transpose into frag-ready layout)
      int a = t & 127, arr = t >> 7;
      const unsigned short* sp = arr == 0 ? Quh : arr == 1 ? Qul
                               : arr == 2 ? Qvh : Qvl;
      *(uint4*)&qs[arr][a >> 4][a & 15][0] =
          *(const uint4*)&sp[((bn << 10) + i0 + (a & 15)) * 64 + (a >> 4) * 8];
    }
    __syncthreads();

    // ---- D^T phase: D[jr][i] = R[jr]·Qv[i], subtiles round-robin over waves
    for (int s = wave; s < NS; s += 8) {
      const size_t kb = (bn * 2048 + (jr0 + s * 16 + i15)) * 64 + g * 8;
      bf16x8 rh0 = *(const bf16x8*)&Rh[kb];
      bf16x8 rh1 = *(const bf16x8*)&Rh[kb + 32];
      bf16x8 rl0 = *(const bf16x8*)&Rl[kb];
      bf16x8 rl1 = *(const bf16x8*)&Rl[kb + 32];
      bf16x8 vh0 = *(const bf16x8*)&qs[2][g][i15][0];
      bf16x8 vh1 = *(const bf16x8*)&qs[2][4 + g][i15][0];
      bf16x8 vl0 = *(const bf16x8*)&qs[3][g][i15][0];
      bf16x8 vl1 = *(const bf16x8*)&qs[3][4 + g][i15][0];
      f32x4 acc = {};
      acc = MFB(rh0, vh0, acc); acc = MFB(rh1, vh1, acc);
      acc = MFB(rh0, vl0, acc); acc = MFB(rh1, vl1, acc);
      acc = MFB(rl0, vh0, acc); acc = MFB(rl1, vh1, acc);
#pragma unroll
      for (int r = 0; r < 4; ++r)
        Dl[i15][s * 16 + g * 4 + r] = (_Float16)acc[r];
    }
    __syncthreads();

    // ---- AC phase: S^T = K·Qu over this wave's 256-j slab
    f32x4 sa[16];
#pragma unroll
    for (int js = 0; js < 16; ++js) sa[js] = (f32x4){};
    {
      bf16x8 uh0 = *(const bf16x8*)&qs[0][g][i15][0];
      bf16x8 uh1 = *(const bf16x8*)&qs[0][4 + g][i15][0];
      bf16x8 ul0 = *(const bf16x8*)&qs[1][g][i15][0];
      bf16x8 ul1 = *(const bf16x8*)&qs[1][4 + g][i15][0];
#pragma unroll 2
      for (int js = 0; js < 16; ++js) {
        const size_t kb = (bn * 2048 + (jb + js * 16 + i15)) * 64 + g * 8;
        bf16x8 kh0 = *(const bf16x8*)&Kh[kb];
        bf16x8 kh1 = *(const bf16x8*)&Kh[kb + 32];
        bf16x8 kl0 = *(const bf16x8*)&Kl[kb];
        bf16x8 kl1 = *(const bf16x8*)&Kl[kb + 32];
        f32x4 a = sa[js];
        a = MFB(kh0, uh0, a); a = MFB(kh1, uh1, a);
        a = MFB(kh0, ul0, a); a = MFB(kh1, ul1, a);
        a = MFB(kl0, uh0, a); a = MFB(kl1, uh1, a);
        sa[js] = a;
      }
    }

    // ---- combine shifted D + mask + scale; per-row max
    float m = -1e30f;
#pragma unroll
    for (int js = 0; js < 16; ++js)
#pragma unroll
      for (int r = 0; r < 4; ++r) {
        int j = jb + js * 16 + g * 4 + r;
        float sv = (sa[js][r] + (float)Dl[i15][j + 15 - i15]) * 0.125f;
        sv = (j <= i0 + i15 + 1024) ? sv : -1e30f;
        sa[js][r] = sv;
        m = fmaxf(m, sv);
      }
    m = fmaxf(m, __shfl_xor(m, 16));
    m = fmaxf(m, __shfl_xor(m, 32));
    if (g == 0) red[0][wave][i15] = m;
    __syncthreads();           // (a) combines done -> Dl reusable; maxes in
    float mi = red[0][0][i15];
#pragma unroll
    for (int w = 1; w < 8; ++w) mi = fmaxf(mi, red[0][w][i15]);
    float l = 0.f;
#pragma unroll
    for (int js = 0; js < 16; ++js)
#pragma unroll
      for (int r = 0; r < 4; ++r) {
        float p = __expf(sa[js][r] - mi);
        sa[js][r] = p; l += p;
      }
    l += __shfl_xor(l, 16);
    l += __shfl_xor(l, 32);
    if (g == 0) red[1][wave][i15] = l;
    __syncthreads();           // (b) sums in
    float li = 0.f;
#pragma unroll
    for (int w = 0; w < 8; ++w) li += red[1][w][i15];
    float rinv = 1.f / li;
#pragma unroll
    for (int js = 0; js < 16; ++js) {
      f16x4 pk;
#pragma unroll
      for (int r = 0; r < 4; ++r) pk[r] = (_Float16)(sa[js][r] * rinv);
      *(f16x4*)&Dl[i15][jb + js * 16 + g * 4] = pk;
    }
    __syncthreads();           // (c) P ready

    // ---- attnacc += P (coalesced, atomic: 2 head-group blocks contend)
    {
      int ii = t & 15, jq = t >> 4;
      float* ap = &attnacc[((size_t)b * 1024 + i0 + ii) * 2048 + jq * 64];
      const _Float16* pp = &Dl[ii][jq * 64];
#pragma unroll
      for (int c = 0; c < 16; ++c) {
        f16x4 pv4 = *(const f16x4*)&pp[c * 4];
#pragma unroll
        for (int k = 0; k < 4; ++k) atomicAdd(ap + c * 4 + k, (float)pv4[k]);
      }
    }

    // ---- PV: vec_partial = P·V over this wave's slab (f16 MFMA)
    f32x4 va[4];
#pragma unroll
    for (int d = 0; d < 4; ++d) va[d] = (f32x4){};
#pragma unroll 2
    for (int kc = 0; kc < 8; ++kc) {
      f16x8 pa = *(const f16x8*)&Dl[i15][jb + kc * 32 + g * 8];
#pragma unroll
      for (int d = 0; d < 4; ++d) {
        f16x8 vb = *(const f16x8*)&VT[(bn * 64 + d * 16 + i15) * 2048 + jb + kc * 32 + g * 8];
        va[d] = MFH(pa, vb, va[d]);
      }
    }
    __syncthreads();           // (d) all P reads done -> Dl as fp32 scratch
    float* sc2 = (float*)&Dl[0][0];
#pragma unroll
    for (int d = 0; d < 4; ++d)
#pragma unroll
      for (int r = 0; r < 4; ++r)
        sc2[(wave * 16 + g * 4 + r) * 64 + d * 16 + i15] = va[d][r];
    __syncthreads();           // (e) partials staged
    {
      int ii = t >> 5, dp = (t & 31) * 2;
      float s0 = 0.f, s1 = 0.f;
#pragma unroll
      for (int w = 0; w < 8; ++w) {
        s0 += sc2[(w * 16 + ii) * 64 + dp];
        s1 += sc2[(w * 16 + ii) * 64 + dp + 1];
      }
      float* vp = &vec[(((size_t)(i0 + ii) * 4 + b) << 10) + n * 64 + dp];
      vp[0] = s0; vp[1] = s1;
    }
    __syncthreads();           // (f) scratch/qs free for next head
  }
}

// ---------------- attn matrix finalize: mean over batch ---------------------
__global__ __launch_bounds__(256) void attnfin_k(const float* __restrict__ acc,
                                                 float* __restrict__ out)
{
  size_t idx = (size_t)blockIdx.x * 256 + threadIdx.x;
  const size_t S = (size_t)XLEN * TOT;
  float s = acc[idx] + acc[idx + S] + acc[idx + 2 * S] + acc[idx + 3 * S];
  out[idx] = s * (1.0f / 64.0f);
}

// ---------------- LayerNorm (+optional bf16 hi/lo split output) -------------
template<int SPLIT>
__global__ __launch_bounds__(256) void ln_k(const float* __restrict__ in,
                                            const float* __restrict__ g,
                                            const float* __restrict__ bb,
                                            float* __restrict__ out,
                                            unsigned short* __restrict__ oh,
                                            unsigned short* __restrict__ ol)
{
  __shared__ float rbuf[8];
  const int row = blockIdx.x;
  const int t = threadIdx.x;
  const float* p = in + (size_t)row * DM;
  float4 v = *(const float4*)(p + t * 4);
  float s1 = v.x + v.y + v.z + v.w;
  float s2 = v.x * v.x + v.y * v.y + v.z * v.z + v.w * v.w;
#pragma unroll
  for (int off = 32; off; off >>= 1) {
    s1 += __shfl_xor(s1, off);
    s2 += __shfl_xor(s2, off);
  }
  const int wv = t >> 6, lane = t & 63;
  if (lane == 0) { rbuf[wv] = s1; rbuf[4 + wv] = s2; }
  __syncthreads();
  if (t == 0) {
    float a = rbuf[0] + rbuf[1] + rbuf[2] + rbuf[3];
    float b2 = rbuf[4] + rbuf[5] + rbuf[6] + rbuf[7];
    float mu = a * (1.f / DM);
    float var = b2 * (1.f / DM) - mu * mu;
    rbuf[0] = mu;
    rbuf[1] = rsqrtf(var + 1e-5f);
  }
  __syncthreads();
  float mu = rbuf[0], rs = rbuf[1];
  float4 gv = *(const float4*)(g + t * 4);
  float4 bv = *(const float4*)(bb + t * 4);
  float4 o;
  o.x = (v.x - mu) * rs * gv.x + bv.x;
  o.y = (v.y - mu) * rs * gv.y + bv.y;
  o.z = (v.z - mu) * rs * gv.z + bv.z;
  o.w = (v.w - mu) * rs * gv.w + bv.w;
  *(float4*)(out + (size_t)row * DM + t * 4) = o;
  if (SPLIT) {
    ushort4 h, l;
    h.x = bf16rn(o.x); l.x = bf16rn(o.x - bf16tof(h.x));
    h.y = bf16rn(o.y); l.y = bf16rn(o.y - bf16tof(h.y));
    h.z = bf16rn(o.z); l.z = bf16rn(o.z - bf16tof(h.z));
    h.w = bf16rn(o.w); l.w = bf16rn(o.w - bf16tof(h.w));
    *(ushort4*)(oh + (size_t)row * DM + t * 4) = h;
    *(ushort4*)(ol + (size_t)row * DM + t * 4) = l;
  }
}

// ---------------- launch ----------------
extern "C" void kernel_launch(void* const* d_in, const int* in_sizes, int n_in,
                              void* d_out, int out_size, void* d_ws, size_t ws_size,
                              hipStream_t stream) {
  const float* x      = (const float*)d_in[0];
  const float* memory = (const float*)d_in[1];
  const float* pos    = (const float*)d_in[2];
  const float* pbu    = (const float*)d_in[3];
  const float* pbv    = (const float*)d_in[4];
  const float* Wq   = (const float*)d_in[6];
  const float* Wkv  = (const float*)d_in[7];
  const float* Wrel = (const float*)d_in[8];
  const float* Wo   = (const float*)d_in[9];
  const float* ln1g = (const float*)d_in[10];
  const float* ln1b = (const float*)d_in[11];
  const float* W1   = (const float*)d_in[12];
  const float* b1   = (const float*)d_in[13];
  const float* W2   = (const float*)d_in[14];
  const float* b2   = (const float*)d_in[15];
  const float* ln2g = (const float*)d_in[16];
  const float* ln2b = (const float*)d_in[17];

  float* out   = (float*)d_out;                    // [1024,4,1024]
  float* attnm = out + (size_t)XLEN * BATCH * DM;  // [1024,2048]
  float* ws = (float*)d_ws;
  const size_t M1 = 1048576;  // 1M floats

  // ---- workspace (offsets in floats; bf16/f16 arrays cast) ----
  unsigned short* c_h   = (unsigned short*)(ws + 0);          // [0,4M)
  unsigned short* c_l   = (unsigned short*)(ws + 4 * M1);     // [4,8M)
  float* pos_f[2] = { ws + 8 * M1, ws + 12 * M1 };            // [8,16M)
  unsigned short* pos_h = (unsigned short*)pos_f[0];
  unsigned short* pos_l = (unsigned short*)pos_f[1];
  unsigned short* Wkvh  = (unsigned short*)(ws + 16 * M1);
  unsigned short* Wkvl  = (unsigned short*)(ws + 17 * M1);
  unsigned short* Wqh   = (unsigned short*)(ws + 18 * M1);
  unsigned short* Wql   = (unsigned short*)(ws + 18 * M1 + M1 / 2);
  unsigned short* Wrelh = (unsigned short*)(ws + 19 * M1);
  unsigned short* Wrell = (unsigned short*)(ws + 19 * M1 + M1 / 2);
  unsigned short* Rh    = (unsigned short*)(ws + 20 * M1);    // [20,24M)
  unsigned short* Rl    = (unsigned short*)(ws + 24 * M1);    // [24,28M)
  unsigned short* Quh   = (unsigned short*)(ws + 28 * M1);    // [28,30M)
  unsigned short* Qul   = (unsigned short*)(ws + 30 * M1);
  unsigned short* Qvh   = (unsigned short*)(ws + 32 * M1);
  unsigned short* Qvl   = (unsigned short*)(ws + 34 * M1);
  unsigned short* Kh    = (unsigned short*)(ws + 8 * M1);     // over pos
  unsigned short* Kl    = (unsigned short*)(ws + 12 * M1);
  unsigned short* VTu   = (unsigned short*)(ws + 36 * M1);    // [36,40M) f16
  float* attnacc        = ws + 0;                              // over c
  float* vec            = ws + 16 * M1;                        // over W splits
  // post-attention
  unsigned short* vech  = (unsigned short*)(ws + 8 * M1);     // over Kh
  unsigned short* vecl  = (unsigned short*)(ws + 10 * M1);
  unsigned short* W1h   = (unsigned short*)(ws + 12 * M1);    // over Kl
  unsigned short* W1l   = (unsigned short*)(ws + 14 * M1);
  unsigned short* W2h   = (unsigned short*)(ws + 0);          // over attnacc
  unsigned short* W2l   = (unsigned short*)(ws + 2 * M1);
  unsigned short* Woh   = (unsigned short*)(ws + 4 * M1);
  unsigned short* Wol   = (unsigned short*)(ws + 4 * M1 + M1 / 2);
  float* t1             = ws + 40 * M1;                        // [40,44M)
  float* h              = ws + 16 * M1;                        // over vec
  unsigned short* hhp   = (unsigned short*)(ws + 20 * M1);    // over Rh
  unsigned short* hlp   = (unsigned short*)(ws + 22 * M1);
  unsigned short* ffph  = (unsigned short*)(ws + 24 * M1);    // [24,32M)
  unsigned short* ffpl  = (unsigned short*)(ws + 32 * M1);    // [32,40M)
  float* t2             = ws + 8 * M1;                         // over vech/vecl

  // 1) pre-attention splits
  split2_k<<<8192, 256, 0, stream>>>(memory, x, MEMLEN * BATCH * DM, c_h, c_l);
  split2_k<<<8192, 256, 0, stream>>>(pos, pos, 1 << 30, pos_h, pos_l);
  tsplit_k<<<dim3(16, 32), 256, 0, stream>>>(Wkv, DM, 2048, Wkvh, Wkvl);
  tsplit_k<<<dim3(16, 16), 256, 0, stream>>>(Wq, DM, 1024, Wqh, Wql);
  tsplit_k<<<dim3(16, 16), 256, 0, stream>>>(Wrel, DM, 1024, Wrelh, Wrell);

  // 2) R = pos@Wrel (pos dead after)
  gemm_k<2><<<dim3(8, 64), 256, 0, stream>>>(pos_h, pos_l, Wrelh, Wrell, 1024, DM,
      nullptr, nullptr, nullptr, Rh, Rl, nullptr, nullptr);
  // 3) Qu,Qv = x@Wq (+biases)
  gemm_k<1><<<dim3(8, 32), 256, 0, stream>>>(c_h + 4194304, c_l + 4194304, Wqh, Wql,
      1024, DM, pbu, pbv, nullptr, Quh, Qul, Qvh, Qvl);
  // 4) K,VT = c@Wkv (K overwrites pos region; c dead after)
  gemm_k<0><<<dim3(16, 64), 256, 0, stream>>>(c_h, c_l, Wkvh, Wkvl, 2048, DM,
      nullptr, nullptr, nullptr, Kh, Kl, VTu, nullptr);
  // 5) zero attnacc (over c region) then attention
  hipMemsetAsync(attnacc, 0, (size_t)8 * M1 * 4, stream);
  attn_k<<<dim3(64, 4, 2), 512, 0, stream>>>(Kh, Kl, Rh, Rl, Quh, Qul, Qvh, Qvl,
      (const _Float16*)VTu, vec, attnacc);
  // 6) attn matrix mean over batch
  attnfin_k<<<(XLEN * TOT) / 256, 256, 0, stream>>>(attnacc, attnm);

  // 7) post-attention splits
  split2_k<<<4096, 256, 0, stream>>>(vec, vec, 1 << 30, vech, vecl);
  tsplit_k<<<dim3(16, 64), 256, 0, stream>>>(W1, DM, DFF, W1h, W1l);
  tsplit_k<<<dim3(64, 16), 256, 0, stream>>>(W2, DFF, 1024, W2h, W2l);
  tsplit_k<<<dim3(16, 16), 256, 0, stream>>>(Wo, DM, 1024, Woh, Wol);

  // 8) attn_out = vec@Wo + x -> t1
  gemm_k<3><<<dim3(8, 32), 256, 0, stream>>>(vech, vecl, Woh, Wol, 1024, DM,
      x, nullptr, t1, nullptr, nullptr, nullptr, nullptr);
  // 9) h = LN1(t1) + bf16 hi/lo
  ln_k<1><<<XLEN * BATCH, 256, 0, stream>>>(t1, ln1g, ln1b, h, hhp, hlp);
  // 10) ffp = relu(h@W1 + b1) bf16 hi/lo
  gemm_k<4><<<dim3(32, 32), 256, 0, stream>>>(hhp, hlp, W1h, W1l, DFF, DM,
      b1, nullptr, nullptr, ffph, ffpl, nullptr, nullptr);
  // 11) t2 = ffp@W2 + b2 + h
  gemm_k<5><<<dim3(8, 32), 256, 0, stream>>>(ffph, ffpl, W2h, W2l, 1024, DFF,
      b2, h, t2, nullptr, nullptr, nullptr, nullptr);
  // 12) out = LN2(t2)
  ln_k<0><<<XLEN * BATCH, 256, 0, stream>>>(t2, ln2g, ln2b, out, nullptr, nullptr);
}

// Round 6
// 1964.036 us; speedup vs baseline: 3.7335x; 3.7335x over previous
//
#include <hip/hip_runtime.h>

#define NHEAD 16
#define DHEAD 64
#define XLEN 1024
#define MEMLEN 1024
#define BATCH 4
#define TOT 2048
#define DFF 4096
#define DM 1024

typedef __attribute__((ext_vector_type(8))) short bf16x8;
typedef __attribute__((ext_vector_type(4))) float f32x4;
typedef __attribute__((ext_vector_type(8))) _Float16 f16x8;
typedef __attribute__((ext_vector_type(4))) _Float16 f16x4;

#define MFB(A, B, C) __builtin_amdgcn_mfma_f32_16x16x32_bf16(A, B, C, 0, 0, 0)
#define MFH(A, B, C) __builtin_amdgcn_mfma_f32_16x16x32_f16(A, B, C, 0, 0, 0)

__device__ __forceinline__ unsigned short bf16rn(float x) {
  union { float f; unsigned u; } c{x};
  unsigned r = c.u + 0x7fffu + ((c.u >> 16) & 1u);
  return (unsigned short)(r >> 16);
}
__device__ __forceinline__ float bf16tof(unsigned short h) {
  union { unsigned u; float f; } c{(unsigned)h << 16};
  return c.f;
}

#define GLOAD_LDS16(gp, lp)                                                    \
  __builtin_amdgcn_global_load_lds(                                            \
      (const __attribute__((address_space(1))) unsigned int*)(gp),             \
      (__attribute__((address_space(3))) unsigned int*)(lp), 16, 0, 0)

// ---------------- elementwise split: fp32 -> bf16 hi + bf16 lo --------------
__global__ __launch_bounds__(256) void split2_k(
    const float* __restrict__ s0, const float* __restrict__ s1, int splitElems,
    unsigned short* __restrict__ oh, unsigned short* __restrict__ ol)
{
  int i4 = (blockIdx.x * 256 + threadIdx.x) * 4;
  const float* src = (i4 < splitElems) ? (s0 + i4) : (s1 + (i4 - splitElems));
  float4 v = *(const float4*)src;
  ushort4 h, l;
  h.x = bf16rn(v.x); l.x = bf16rn(v.x - bf16tof(h.x));
  h.y = bf16rn(v.y); l.y = bf16rn(v.y - bf16tof(h.y));
  h.z = bf16rn(v.z); l.z = bf16rn(v.z - bf16tof(h.z));
  h.w = bf16rn(v.w); l.w = bf16rn(v.w - bf16tof(h.w));
  *(ushort4*)(oh + i4) = h;
  *(ushort4*)(ol + i4) = l;
}

// ------------- transpose + split: W[K][N] fp32 -> Wt hi/lo [N][K] bf16 ------
__global__ __launch_bounds__(256) void tsplit_k(
    const float* __restrict__ W, int K, int N,
    unsigned short* __restrict__ oh, unsigned short* __restrict__ ol)
{
  __shared__ float tile[64][65];
  const int t = threadIdx.x;
  const int bk = blockIdx.x * 64, bn = blockIdx.y * 64;
#pragma unroll
  for (int r = 0; r < 4; ++r) {
    int lr = r * 16 + (t >> 4), lc = (t & 15) * 4;
    *(float4*)&tile[lr][lc] = *(const float4*)&W[(size_t)(bk + lr) * N + bn + lc];
  }
  __syncthreads();
  const int n = t >> 2, kq = t & 3;
  unsigned short* ph = oh + (size_t)(bn + n) * K + bk + kq * 16;
  unsigned short* pl = ol + (size_t)(bn + n) * K + bk + kq * 16;
#pragma unroll
  for (int c = 0; c < 4; ++c) {
    ushort4 h, l;
    float v0 = tile[kq * 16 + c * 4 + 0][n];
    float v1 = tile[kq * 16 + c * 4 + 1][n];
    float v2 = tile[kq * 16 + c * 4 + 2][n];
    float v3 = tile[kq * 16 + c * 4 + 3][n];
    h.x = bf16rn(v0); l.x = bf16rn(v0 - bf16tof(h.x));
    h.y = bf16rn(v1); l.y = bf16rn(v1 - bf16tof(h.y));
    h.z = bf16rn(v2); l.z = bf16rn(v2 - bf16tof(h.z));
    h.w = bf16rn(v3); l.w = bf16rn(v3 - bf16tof(h.w));
    *(ushort4*)(ph + c * 4) = h;
    *(ushort4*)(pl + c * 4) = l;
  }
}

// ---------------- MFMA GEMM: 128x128 tile, 3-term Markidis ------------------
template<int MODE>
__global__ __launch_bounds__(256) void gemm_k(
    const unsigned short* __restrict__ Ah, const unsigned short* __restrict__ Al,
    const unsigned short* __restrict__ Bh, const unsigned short* __restrict__ Bl,
    int N, int K,
    const float* __restrict__ e0, const float* __restrict__ e1,
    float* __restrict__ o0,
    unsigned short* __restrict__ p0, unsigned short* __restrict__ p1,
    unsigned short* __restrict__ p2, unsigned short* __restrict__ p3)
{
  __shared__ unsigned short lds[4][4096];  // Ah,Al,Bh,Bl: 128 rows x 32 bf16
  const int t = threadIdx.x;
  const int wave = t >> 6, lane = t & 63;
  const int wm = wave >> 1, wn = wave & 1;
  const int m0 = blockIdx.y * 128, n0 = blockIdx.x * 128;

  const unsigned short* gp[2][4];
  unsigned short* lp[2][4];
#pragma unroll
  for (int i = 0; i < 2; ++i) {
    int s = i * 256 + t, row = s >> 2, sl = s & 3;
    int csw = (sl ^ (row & 3)) * 8;
    gp[i][0] = Ah + (size_t)(m0 + row) * K + csw;
    gp[i][1] = Al + (size_t)(m0 + row) * K + csw;
    gp[i][2] = Bh + (size_t)(n0 + row) * K + csw;
    gp[i][3] = Bl + (size_t)(n0 + row) * K + csw;
#pragma unroll
    for (int a = 0; a < 4; ++a) lp[i][a] = &lds[a][s * 8];
  }

  f32x4 acc[4][4] = {};
  const int kg = lane >> 4, r15 = lane & 15;

  for (int k0 = 0; k0 < K; k0 += 32) {
#pragma unroll
    for (int i = 0; i < 2; ++i)
#pragma unroll
      for (int a = 0; a < 4; ++a) GLOAD_LDS16(gp[i][a] + k0, lp[i][a]);
    __syncthreads();

    bf16x8 afh[4], afl[4], bfh[4], bfl[4];
#pragma unroll
    for (int f = 0; f < 4; ++f) {
      int rowA = wm * 64 + f * 16 + r15;
      int ia = (rowA * 4 + (kg ^ (rowA & 3))) * 8;
      afh[f] = *(const bf16x8*)&lds[0][ia];
      afl[f] = *(const bf16x8*)&lds[1][ia];
      int rowB = wn * 64 + f * 16 + r15;
      int ib = (rowB * 4 + (kg ^ (rowB & 3))) * 8;
      bfh[f] = *(const bf16x8*)&lds[2][ib];
      bfl[f] = *(const bf16x8*)&lds[3][ib];
    }
#pragma unroll
    for (int i = 0; i < 4; ++i)
#pragma unroll
      for (int j = 0; j < 4; ++j) {
        acc[i][j] = MFB(afh[i], bfh[j], acc[i][j]);
        acc[i][j] = MFB(afh[i], bfl[j], acc[i][j]);
        acc[i][j] = MFB(afl[i], bfh[j], acc[i][j]);
      }
    __syncthreads();
  }

  // epilogue: C/D layout col = lane&15, row = (lane>>4)*4 + reg
#pragma unroll
  for (int i = 0; i < 4; ++i)
#pragma unroll
    for (int j = 0; j < 4; ++j)
#pragma unroll
      for (int r = 0; r < 4; ++r) {
        int m = m0 + wm * 64 + i * 16 + kg * 4 + r;
        int nn = n0 + wn * 64 + j * 16 + r15;
        float v = acc[i][j][r];
        if (MODE == 0) {           // c@Wkv -> Kh/Kl [B,N,T,64], VT f16 [B,N,64,T]
          int tt = m >> 2, bb = m & 3;
          if (nn < 1024) {
            int hn = nn >> 6, d = nn & 63;
            size_t idx = ((size_t)(bb * 16 + hn) * 2048 + tt) * 64 + d;
            unsigned short hi = bf16rn(v);
            p0[idx] = hi; p1[idx] = bf16rn(v - bf16tof(hi));
          } else {
            int c2 = nn - 1024, hn = c2 >> 6, d = c2 & 63;
            union { _Float16 h; unsigned short u; } cv; cv.h = (_Float16)v;
            p2[((size_t)(bb * 16 + hn) * 64 + d) * 2048 + tt] = cv.u;
          }
        } else if (MODE == 1) {    // x@Wq + biases -> Quh/Qul/Qvh/Qvl [B,N,I,64]
          int i2 = m >> 2, bb = m & 3;
          int hn = nn >> 6, d = nn & 63;
          size_t idx = ((size_t)(bb * 16 + hn) * 1024 + i2) * 64 + d;
          float vu = v + e0[nn], vv = v + e1[nn];
          unsigned short h0 = bf16rn(vu);
          p0[idx] = h0; p1[idx] = bf16rn(vu - bf16tof(h0));
          unsigned short h1 = bf16rn(vv);
          p2[idx] = h1; p3[idx] = bf16rn(vv - bf16tof(h1));
        } else if (MODE == 2) {    // pos@Wrel -> Rh/Rl [B,N,T,64]
          int tt = m >> 2, bb = m & 3;
          int hn = nn >> 6, d = nn & 63;
          size_t idx = ((size_t)(bb * 16 + hn) * 2048 + tt) * 64 + d;
          unsigned short hi = bf16rn(v);
          p0[idx] = hi; p1[idx] = bf16rn(v - bf16tof(hi));
        } else if (MODE == 3) {    // vec@Wo + x -> t1 (fp32)
          o0[(size_t)m * N + nn] = v + e0[(size_t)m * N + nn];
        } else if (MODE == 4) {    // relu(h@W1 + b1) -> ffp hi/lo bf16
          float v2 = fmaxf(v + e0[nn], 0.f);
          unsigned short hh = bf16rn(v2);
          p0[(size_t)m * N + nn] = hh;
          p1[(size_t)m * N + nn] = bf16rn(v2 - bf16tof(hh));
        } else if (MODE == 5) {    // ff@W2 + b2 + h -> t2 (fp32)
          o0[(size_t)m * N + nn] = v + e0[nn] + e1[(size_t)m * N + nn];
        }
      }
}

// ---------------- MFMA attention ----------------
// block = (16 q-rows, b, 8-head group); 8 waves; swapped-operand S^T so each
// lane holds one q-row's 64 scores in regs. D (rel-pos) via MFMA into f16 LDS
// window; exact per-row fp32 softmax; PV via f16 MFMA. P head-sum accumulated
// in packed-f16 registers, stored ONCE per block (no atomics — round-5 lesson:
// 134M atomicAdds caused 8GB of memory-side RMW traffic).
__global__ __launch_bounds__(512, 4) void attn_k(
    const unsigned short* __restrict__ Kh, const unsigned short* __restrict__ Kl,
    const unsigned short* __restrict__ Rh, const unsigned short* __restrict__ Rl,
    const unsigned short* __restrict__ Quh, const unsigned short* __restrict__ Qul,
    const unsigned short* __restrict__ Qvh, const unsigned short* __restrict__ Qvl,
    const _Float16* __restrict__ VT,
    float* __restrict__ vec, float* __restrict__ acc0, float* __restrict__ acc1)
{
  __shared__ _Float16 Dl[16][2072];            // D window, then normalized P
  __shared__ unsigned short qs[4][8][16][8];   // Q^T frags: arr, dchunk, i, e
  __shared__ float red[2][8][16];
  const int t = threadIdx.x, wave = t >> 6, lane = t & 63;
  const int g = lane >> 4, i15 = lane & 15;
  const int i0 = blockIdx.x * 16, b = blockIdx.y;
  const int jr0 = 1008 - i0;
  const int NS = (2048 - jr0) >> 4;
  const int jb = wave * 256;

  f16x4 pacc[16];
#pragma unroll
  for (int js = 0; js < 16; ++js) pacc[js] = (f16x4){};

  for (int hh = 0; hh < 8; ++hh) {
    const int n = blockIdx.z * 8 + hh;
    const size_t bn = (size_t)(b * 16 + n);

    {  // stage Q^T tiles (transpose into frag-ready layout)
      int a = t & 127, arr = t >> 7;
      const unsigned short* sp = arr == 0 ? Quh : arr == 1 ? Qul
                               : arr == 2 ? Qvh : Qvl;
      *(uint4*)&qs[arr][a >> 4][a & 15][0] =
          *(const uint4*)&sp[((bn << 10) + i0 + (a & 15)) * 64 + (a >> 4) * 8];
    }
    __syncthreads();

    // ---- D^T phase: D[jr][i] = R[jr]·Qv[i], subtiles round-robin over waves
    for (int s = wave; s < NS; s += 8) {
      const size_t kb = (bn * 2048 + (jr0 + s * 16 + i15)) * 64 + g * 8;
      bf16x8 rh0 = *(const bf16x8*)&Rh[kb];
      bf16x8 rh1 = *(const bf16x8*)&Rh[kb + 32];
      bf16x8 rl0 = *(const bf16x8*)&Rl[kb];
      bf16x8 rl1 = *(const bf16x8*)&Rl[kb + 32];
      bf16x8 vh0 = *(const bf16x8*)&qs[2][g][i15][0];
      bf16x8 vh1 = *(const bf16x8*)&qs[2][4 + g][i15][0];
      bf16x8 vl0 = *(const bf16x8*)&qs[3][g][i15][0];
      bf16x8 vl1 = *(const bf16x8*)&qs[3][4 + g][i15][0];
      f32x4 acc = {};
      acc = MFB(rh0, vh0, acc); acc = MFB(rh1, vh1, acc);
      acc = MFB(rh0, vl0, acc); acc = MFB(rh1, vl1, acc);
      acc = MFB(rl0, vh0, acc); acc = MFB(rl1, vh1, acc);
#pragma unroll
      for (int r = 0; r < 4; ++r)
        Dl[i15][s * 16 + g * 4 + r] = (_Float16)acc[r];
    }
    __syncthreads();

    // ---- AC phase: S^T = K·Qu over this wave's 256-j slab
    f32x4 sa[16];
#pragma unroll
    for (int js = 0; js < 16; ++js) sa[js] = (f32x4){};
    {
      bf16x8 uh0 = *(const bf16x8*)&qs[0][g][i15][0];
      bf16x8 uh1 = *(const bf16x8*)&qs[0][4 + g][i15][0];
      bf16x8 ul0 = *(const bf16x8*)&qs[1][g][i15][0];
      bf16x8 ul1 = *(const bf16x8*)&qs[1][4 + g][i15][0];
#pragma unroll 2
      for (int js = 0; js < 16; ++js) {
        const size_t kb = (bn * 2048 + (jb + js * 16 + i15)) * 64 + g * 8;
        bf16x8 kh0 = *(const bf16x8*)&Kh[kb];
        bf16x8 kh1 = *(const bf16x8*)&Kh[kb + 32];
        bf16x8 kl0 = *(const bf16x8*)&Kl[kb];
        bf16x8 kl1 = *(const bf16x8*)&Kl[kb + 32];
        f32x4 a = sa[js];
        a = MFB(kh0, uh0, a); a = MFB(kh1, uh1, a);
        a = MFB(kh0, ul0, a); a = MFB(kh1, ul1, a);
        a = MFB(kl0, uh0, a); a = MFB(kl1, uh1, a);
        sa[js] = a;
      }
    }

    // ---- combine shifted D + mask + scale; per-row max
    float m = -1e30f;
#pragma unroll
    for (int js = 0; js < 16; ++js)
#pragma unroll
      for (int r = 0; r < 4; ++r) {
        int j = jb + js * 16 + g * 4 + r;
        float sv = (sa[js][r] + (float)Dl[i15][j + 15 - i15]) * 0.125f;
        sv = (j <= i0 + i15 + 1024) ? sv : -1e30f;
        sa[js][r] = sv;
        m = fmaxf(m, sv);
      }
    m = fmaxf(m, __shfl_xor(m, 16));
    m = fmaxf(m, __shfl_xor(m, 32));
    if (g == 0) red[0][wave][i15] = m;
    __syncthreads();           // (a) combines done -> Dl reusable; maxes in
    float mi = red[0][0][i15];
#pragma unroll
    for (int w = 1; w < 8; ++w) mi = fmaxf(mi, red[0][w][i15]);
    float l = 0.f;
#pragma unroll
    for (int js = 0; js < 16; ++js)
#pragma unroll
      for (int r = 0; r < 4; ++r) {
        float p = __expf(sa[js][r] - mi);
        sa[js][r] = p; l += p;
      }
    l += __shfl_xor(l, 16);
    l += __shfl_xor(l, 32);
    if (g == 0) red[1][wave][i15] = l;
    __syncthreads();           // (b) sums in
    float li = 0.f;
#pragma unroll
    for (int w = 0; w < 8; ++w) li += red[1][w][i15];
    float rinv = 1.f / li;
#pragma unroll
    for (int js = 0; js < 16; ++js) {
      f16x4 pk;
#pragma unroll
      for (int r = 0; r < 4; ++r) pk[r] = (_Float16)(sa[js][r] * rinv);
      *(f16x4*)&Dl[i15][jb + js * 16 + g * 4] = pk;
      pacc[js] += pk;          // head-sum accumulation in registers
    }
    __syncthreads();           // (c) P ready

    // ---- PV: vec_partial = P·V over this wave's slab (f16 MFMA)
    f32x4 va[4];
#pragma unroll
    for (int d = 0; d < 4; ++d) va[d] = (f32x4){};
#pragma unroll 2
    for (int kc = 0; kc < 8; ++kc) {
      f16x8 pa = *(const f16x8*)&Dl[i15][jb + kc * 32 + g * 8];
#pragma unroll
      for (int d = 0; d < 4; ++d) {
        f16x8 vb = *(const f16x8*)&VT[(bn * 64 + d * 16 + i15) * 2048 + jb + kc * 32 + g * 8];
        va[d] = MFH(pa, vb, va[d]);
      }
    }
    __syncthreads();           // (d) all P reads done -> Dl as fp32 scratch
    float* sc2 = (float*)&Dl[0][0];
#pragma unroll
    for (int d = 0; d < 4; ++d)
#pragma unroll
      for (int r = 0; r < 4; ++r)
        sc2[(wave * 16 + g * 4 + r) * 64 + d * 16 + i15] = va[d][r];
    __syncthreads();           // (e) partials staged
    {
      int ii = t >> 5, dp = (t & 31) * 2;
      float s0 = 0.f, s1 = 0.f;
#pragma unroll
      for (int w = 0; w < 8; ++w) {
        s0 += sc2[(w * 16 + ii) * 64 + dp];
        s1 += sc2[(w * 16 + ii) * 64 + dp + 1];
      }
      float* vp = &vec[(((size_t)(i0 + ii) * 4 + b) << 10) + n * 64 + dp];
      vp[0] = s0; vp[1] = s1;
    }
    __syncthreads();           // (f) scratch/qs free for next head
  }

  // ---- write head-summed P once (block-exclusive region, no atomics)
  {
    float* ap = blockIdx.z ? acc1 : acc0;
    float* rp = &ap[((size_t)b * 1024 + i0 + i15) * 2048];
#pragma unroll
    for (int js = 0; js < 16; ++js) {
      float4 o;
      o.x = (float)pacc[js][0]; o.y = (float)pacc[js][1];
      o.z = (float)pacc[js][2]; o.w = (float)pacc[js][3];
      *(float4*)&rp[jb + js * 16 + g * 4] = o;
    }
  }
}

// ---------------- attn matrix finalize: mean over batch + z-halves ----------
__global__ __launch_bounds__(256) void attnfin_k(const float* __restrict__ a0,
                                                 const float* __restrict__ a1,
                                                 float* __restrict__ out)
{
  size_t idx = (size_t)blockIdx.x * 256 + threadIdx.x;
  const size_t S = (size_t)XLEN * TOT;
  float s = 0.f;
#pragma unroll
  for (int b = 0; b < 4; ++b) s += a0[idx + b * S] + a1[idx + b * S];
  out[idx] = s * (1.0f / 64.0f);
}

// ---------------- LayerNorm (+optional bf16 hi/lo split output) -------------
template<int SPLIT>
__global__ __launch_bounds__(256) void ln_k(const float* __restrict__ in,
                                            const float* __restrict__ g,
                                            const float* __restrict__ bb,
                                            float* __restrict__ out,
                                            unsigned short* __restrict__ oh,
                                            unsigned short* __restrict__ ol)
{
  __shared__ float rbuf[8];
  const int row = blockIdx.x;
  const int t = threadIdx.x;
  const float* p = in + (size_t)row * DM;
  float4 v = *(const float4*)(p + t * 4);
  float s1 = v.x + v.y + v.z + v.w;
  float s2 = v.x * v.x + v.y * v.y + v.z * v.z + v.w * v.w;
#pragma unroll
  for (int off = 32; off; off >>= 1) {
    s1 += __shfl_xor(s1, off);
    s2 += __shfl_xor(s2, off);
  }
  const int wv = t >> 6, lane = t & 63;
  if (lane == 0) { rbuf[wv] = s1; rbuf[4 + wv] = s2; }
  __syncthreads();
  if (t == 0) {
    float a = rbuf[0] + rbuf[1] + rbuf[2] + rbuf[3];
    float b2 = rbuf[4] + rbuf[5] + rbuf[6] + rbuf[7];
    float mu = a * (1.f / DM);
    float var = b2 * (1.f / DM) - mu * mu;
    rbuf[0] = mu;
    rbuf[1] = rsqrtf(var + 1e-5f);
  }
  __syncthreads();
  float mu = rbuf[0], rs = rbuf[1];
  float4 gv = *(const float4*)(g + t * 4);
  float4 bv = *(const float4*)(bb + t * 4);
  float4 o;
  o.x = (v.x - mu) * rs * gv.x + bv.x;
  o.y = (v.y - mu) * rs * gv.y + bv.y;
  o.z = (v.z - mu) * rs * gv.z + bv.z;
  o.w = (v.w - mu) * rs * gv.w + bv.w;
  *(float4*)(out + (size_t)row * DM + t * 4) = o;
  if (SPLIT) {
    ushort4 h, l;
    h.x = bf16rn(o.x); l.x = bf16rn(o.x - bf16tof(h.x));
    h.y = bf16rn(o.y); l.y = bf16rn(o.y - bf16tof(h.y));
    h.z = bf16rn(o.z); l.z = bf16rn(o.z - bf16tof(h.z));
    h.w = bf16rn(o.w); l.w = bf16rn(o.w - bf16tof(h.w));
    *(ushort4*)(oh + (size_t)row * DM + t * 4) = h;
    *(ushort4*)(ol + (size_t)row * DM + t * 4) = l;
  }
}

// ---------------- launch ----------------
extern "C" void kernel_launch(void* const* d_in, const int* in_sizes, int n_in,
                              void* d_out, int out_size, void* d_ws, size_t ws_size,
                              hipStream_t stream) {
  const float* x      = (const float*)d_in[0];
  const float* memory = (const float*)d_in[1];
  const float* pos    = (const float*)d_in[2];
  const float* pbu    = (const float*)d_in[3];
  const float* pbv    = (const float*)d_in[4];
  const float* Wq   = (const float*)d_in[6];
  const float* Wkv  = (const float*)d_in[7];
  const float* Wrel = (const float*)d_in[8];
  const float* Wo   = (const float*)d_in[9];
  const float* ln1g = (const float*)d_in[10];
  const float* ln1b = (const float*)d_in[11];
  const float* W1   = (const float*)d_in[12];
  const float* b1   = (const float*)d_in[13];
  const float* W2   = (const float*)d_in[14];
  const float* b2   = (const float*)d_in[15];
  const float* ln2g = (const float*)d_in[16];
  const float* ln2b = (const float*)d_in[17];

  float* out   = (float*)d_out;                    // [1024,4,1024]
  float* attnm = out + (size_t)XLEN * BATCH * DM;  // [1024,2048]
  float* ws = (float*)d_ws;
  const size_t M1 = 1048576;  // 1M floats

  // ---- workspace (offsets in floats; bf16/f16 arrays cast) ----
  unsigned short* c_h   = (unsigned short*)(ws + 0);          // [0,4M)
  unsigned short* c_l   = (unsigned short*)(ws + 4 * M1);     // [4,8M)
  float* pos_f[2] = { ws + 8 * M1, ws + 12 * M1 };            // [8,16M)
  unsigned short* pos_h = (unsigned short*)pos_f[0];
  unsigned short* pos_l = (unsigned short*)pos_f[1];
  unsigned short* Wkvh  = (unsigned short*)(ws + 16 * M1);
  unsigned short* Wkvl  = (unsigned short*)(ws + 17 * M1);
  unsigned short* Wqh   = (unsigned short*)(ws + 18 * M1);
  unsigned short* Wql   = (unsigned short*)(ws + 18 * M1 + M1 / 2);
  unsigned short* Wrelh = (unsigned short*)(ws + 19 * M1);
  unsigned short* Wrell = (unsigned short*)(ws + 19 * M1 + M1 / 2);
  unsigned short* Rh    = (unsigned short*)(ws + 20 * M1);    // [20,24M)
  unsigned short* Rl    = (unsigned short*)(ws + 24 * M1);    // [24,28M)
  unsigned short* Quh   = (unsigned short*)(ws + 28 * M1);    // [28,30M)
  unsigned short* Qul   = (unsigned short*)(ws + 30 * M1);
  unsigned short* Qvh   = (unsigned short*)(ws + 32 * M1);
  unsigned short* Qvl   = (unsigned short*)(ws + 34 * M1);
  unsigned short* Kh    = (unsigned short*)(ws + 8 * M1);     // over pos
  unsigned short* Kl    = (unsigned short*)(ws + 12 * M1);
  unsigned short* VTu   = (unsigned short*)(ws + 36 * M1);    // [36,40M) f16
  float* attnacc0       = ws + 0;                              // over c [0,8M)
  float* attnacc1       = ws + 44 * M1;                        // [44,52M)
  float* vec            = ws + 16 * M1;                        // over W splits
  // post-attention
  unsigned short* vech  = (unsigned short*)(ws + 8 * M1);     // over Kh
  unsigned short* vecl  = (unsigned short*)(ws + 10 * M1);
  unsigned short* W1h   = (unsigned short*)(ws + 12 * M1);    // over Kl
  unsigned short* W1l   = (unsigned short*)(ws + 14 * M1);
  unsigned short* W2h   = (unsigned short*)(ws + 0);          // over attnacc0
  unsigned short* W2l   = (unsigned short*)(ws + 2 * M1);
  unsigned short* Woh   = (unsigned short*)(ws + 4 * M1);
  unsigned short* Wol   = (unsigned short*)(ws + 4 * M1 + M1 / 2);
  float* t1             = ws + 40 * M1;                        // [40,44M)
  float* h              = ws + 16 * M1;                        // over vec
  unsigned short* hhp   = (unsigned short*)(ws + 20 * M1);    // over Rh
  unsigned short* hlp   = (unsigned short*)(ws + 22 * M1);
  unsigned short* ffph  = (unsigned short*)(ws + 24 * M1);    // [24,32M)
  unsigned short* ffpl  = (unsigned short*)(ws + 32 * M1);    // [32,40M)
  float* t2             = ws + 8 * M1;                         // over vech/vecl

  // 1) pre-attention splits
  split2_k<<<8192, 256, 0, stream>>>(memory, x, MEMLEN * BATCH * DM, c_h, c_l);
  split2_k<<<8192, 256, 0, stream>>>(pos, pos, 1 << 30, pos_h, pos_l);
  tsplit_k<<<dim3(16, 32), 256, 0, stream>>>(Wkv, DM, 2048, Wkvh, Wkvl);
  tsplit_k<<<dim3(16, 16), 256, 0, stream>>>(Wq, DM, 1024, Wqh, Wql);
  tsplit_k<<<dim3(16, 16), 256, 0, stream>>>(Wrel, DM, 1024, Wrelh, Wrell);

  // 2) R = pos@Wrel (pos dead after)
  gemm_k<2><<<dim3(8, 64), 256, 0, stream>>>(pos_h, pos_l, Wrelh, Wrell, 1024, DM,
      nullptr, nullptr, nullptr, Rh, Rl, nullptr, nullptr);
  // 3) Qu,Qv = x@Wq (+biases)
  gemm_k<1><<<dim3(8, 32), 256, 0, stream>>>(c_h + 4194304, c_l + 4194304, Wqh, Wql,
      1024, DM, pbu, pbv, nullptr, Quh, Qul, Qvh, Qvl);
  // 4) K,VT = c@Wkv (K overwrites pos region; c dead after)
  gemm_k<0><<<dim3(16, 64), 256, 0, stream>>>(c_h, c_l, Wkvh, Wkvl, 2048, DM,
      nullptr, nullptr, nullptr, Kh, Kl, VTu, nullptr);
  // 5) attention (P head-sums written exclusively; no zeroing needed)
  attn_k<<<dim3(64, 4, 2), 512, 0, stream>>>(Kh, Kl, Rh, Rl, Quh, Qul, Qvh, Qvl,
      (const _Float16*)VTu, vec, attnacc0, attnacc1);
  // 6) attn matrix mean over batch
  attnfin_k<<<(XLEN * TOT) / 256, 256, 0, stream>>>(attnacc0, attnacc1, attnm);

  // 7) post-attention splits
  split2_k<<<4096, 256, 0, stream>>>(vec, vec, 1 << 30, vech, vecl);
  tsplit_k<<<dim3(16, 64), 256, 0, stream>>>(W1, DM, DFF, W1h, W1l);
  tsplit_k<<<dim3(64, 16), 256, 0, stream>>>(W2, DFF, 1024, W2h, W2l);
  tsplit_k<<<dim3(16, 16), 256, 0, stream>>>(Wo, DM, 1024, Woh, Wol);

  // 8) attn_out = vec@Wo + x -> t1
  gemm_k<3><<<dim3(8, 32), 256, 0, stream>>>(vech, vecl, Woh, Wol, 1024, DM,
      x, nullptr, t1, nullptr, nullptr, nullptr, nullptr);
  // 9) h = LN1(t1) + bf16 hi/lo
  ln_k<1><<<XLEN * BATCH, 256, 0, stream>>>(t1, ln1g, ln1b, h, hhp, hlp);
  // 10) ffp = relu(h@W1 + b1) bf16 hi/lo
  gemm_k<4><<<dim3(32, 32), 256, 0, stream>>>(hhp, hlp, W1h, W1l, DFF, DM,
      b1, nullptr, nullptr, ffph, ffpl, nullptr, nullptr);
  // 11) t2 = ffp@W2 + b2 + h
  gemm_k<5><<<dim3(8, 32), 256, 0, stream>>>(ffph, ffpl, W2h, W2l, 1024, DFF,
      b2, h, t2, nullptr, nullptr, nullptr, nullptr);
  // 12) out = LN2(t2)
  ln_k<0><<<XLEN * BATCH, 256, 0, stream>>>(t2, ln2g, ln2b, out, nullptr, nullptr);
}

// Round 7
// 1859.297 us; speedup vs baseline: 3.9438x; 1.0563x over previous
//
#include <hip/hip_runtime.h>

#define NHEAD 16
#define DHEAD 64
#define XLEN 1024
#define MEMLEN 1024
#define BATCH 4
#define TOT 2048
#define DFF 4096
#define DM 1024

typedef __attribute__((ext_vector_type(8))) short bf16x8;
typedef __attribute__((ext_vector_type(4))) float f32x4;
typedef __attribute__((ext_vector_type(8))) _Float16 f16x8;
typedef __attribute__((ext_vector_type(4))) _Float16 f16x4;

#define MFB(A, B, C) __builtin_amdgcn_mfma_f32_16x16x32_bf16(A, B, C, 0, 0, 0)
#define MFH(A, B, C) __builtin_amdgcn_mfma_f32_16x16x32_f16(A, B, C, 0, 0, 0)

__device__ __forceinline__ unsigned short bf16rn(float x) {
  union { float f; unsigned u; } c{x};
  unsigned r = c.u + 0x7fffu + ((c.u >> 16) & 1u);
  return (unsigned short)(r >> 16);
}
__device__ __forceinline__ float bf16tof(unsigned short h) {
  union { unsigned u; float f; } c{(unsigned)h << 16};
  return c.f;
}

#define GLOAD_LDS16(gp, lp)                                                    \
  __builtin_amdgcn_global_load_lds(                                            \
      (const __attribute__((address_space(1))) unsigned int*)(gp),             \
      (__attribute__((address_space(3))) unsigned int*)(lp), 16, 0, 0)

// ---------------- elementwise split: fp32 -> bf16 hi + bf16 lo --------------
__global__ __launch_bounds__(256) void split2_k(
    const float* __restrict__ s0, const float* __restrict__ s1, int splitElems,
    unsigned short* __restrict__ oh, unsigned short* __restrict__ ol)
{
  int i4 = (blockIdx.x * 256 + threadIdx.x) * 4;
  const float* src = (i4 < splitElems) ? (s0 + i4) : (s1 + (i4 - splitElems));
  float4 v = *(const float4*)src;
  ushort4 h, l;
  h.x = bf16rn(v.x); l.x = bf16rn(v.x - bf16tof(h.x));
  h.y = bf16rn(v.y); l.y = bf16rn(v.y - bf16tof(h.y));
  h.z = bf16rn(v.z); l.z = bf16rn(v.z - bf16tof(h.z));
  h.w = bf16rn(v.w); l.w = bf16rn(v.w - bf16tof(h.w));
  *(ushort4*)(oh + i4) = h;
  *(ushort4*)(ol + i4) = l;
}

// ------------- transpose + split: W[K][N] fp32 -> Wt hi/lo [N][K] bf16 ------
__global__ __launch_bounds__(256) void tsplit_k(
    const float* __restrict__ W, int K, int N,
    unsigned short* __restrict__ oh, unsigned short* __restrict__ ol)
{
  __shared__ float tile[64][65];
  const int t = threadIdx.x;
  const int bk = blockIdx.x * 64, bn = blockIdx.y * 64;
#pragma unroll
  for (int r = 0; r < 4; ++r) {
    int lr = r * 16 + (t >> 4), lc = (t & 15) * 4;
    *(float4*)&tile[lr][lc] = *(const float4*)&W[(size_t)(bk + lr) * N + bn + lc];
  }
  __syncthreads();
  const int n = t >> 2, kq = t & 3;
  unsigned short* ph = oh + (size_t)(bn + n) * K + bk + kq * 16;
  unsigned short* pl = ol + (size_t)(bn + n) * K + bk + kq * 16;
#pragma unroll
  for (int c = 0; c < 4; ++c) {
    ushort4 h, l;
    float v0 = tile[kq * 16 + c * 4 + 0][n];
    float v1 = tile[kq * 16 + c * 4 + 1][n];
    float v2 = tile[kq * 16 + c * 4 + 2][n];
    float v3 = tile[kq * 16 + c * 4 + 3][n];
    h.x = bf16rn(v0); l.x = bf16rn(v0 - bf16tof(h.x));
    h.y = bf16rn(v1); l.y = bf16rn(v1 - bf16tof(h.y));
    h.z = bf16rn(v2); l.z = bf16rn(v2 - bf16tof(h.z));
    h.w = bf16rn(v3); l.w = bf16rn(v3 - bf16tof(h.w));
    *(ushort4*)(ph + c * 4) = h;
    *(ushort4*)(pl + c * 4) = l;
  }
}

// ---------------- MFMA GEMM: 128x128 tile, 3-term Markidis ------------------
template<int MODE>
__global__ __launch_bounds__(256) void gemm_k(
    const unsigned short* __restrict__ Ah, const unsigned short* __restrict__ Al,
    const unsigned short* __restrict__ Bh, const unsigned short* __restrict__ Bl,
    int N, int K,
    const float* __restrict__ e0, const float* __restrict__ e1,
    float* __restrict__ o0,
    unsigned short* __restrict__ p0, unsigned short* __restrict__ p1,
    unsigned short* __restrict__ p2, unsigned short* __restrict__ p3)
{
  __shared__ unsigned short lds[4][4096];  // Ah,Al,Bh,Bl: 128 rows x 32 bf16
  const int t = threadIdx.x;
  const int wave = t >> 6, lane = t & 63;
  const int wm = wave >> 1, wn = wave & 1;
  const int m0 = blockIdx.y * 128, n0 = blockIdx.x * 128;

  const unsigned short* gp[2][4];
  unsigned short* lp[2][4];
#pragma unroll
  for (int i = 0; i < 2; ++i) {
    int s = i * 256 + t, row = s >> 2, sl = s & 3;
    int csw = (sl ^ (row & 3)) * 8;
    gp[i][0] = Ah + (size_t)(m0 + row) * K + csw;
    gp[i][1] = Al + (size_t)(m0 + row) * K + csw;
    gp[i][2] = Bh + (size_t)(n0 + row) * K + csw;
    gp[i][3] = Bl + (size_t)(n0 + row) * K + csw;
#pragma unroll
    for (int a = 0; a < 4; ++a) lp[i][a] = &lds[a][s * 8];
  }

  f32x4 acc[4][4] = {};
  const int kg = lane >> 4, r15 = lane & 15;

  for (int k0 = 0; k0 < K; k0 += 32) {
#pragma unroll
    for (int i = 0; i < 2; ++i)
#pragma unroll
      for (int a = 0; a < 4; ++a) GLOAD_LDS16(gp[i][a] + k0, lp[i][a]);
    __syncthreads();

    bf16x8 afh[4], afl[4], bfh[4], bfl[4];
#pragma unroll
    for (int f = 0; f < 4; ++f) {
      int rowA = wm * 64 + f * 16 + r15;
      int ia = (rowA * 4 + (kg ^ (rowA & 3))) * 8;
      afh[f] = *(const bf16x8*)&lds[0][ia];
      afl[f] = *(const bf16x8*)&lds[1][ia];
      int rowB = wn * 64 + f * 16 + r15;
      int ib = (rowB * 4 + (kg ^ (rowB & 3))) * 8;
      bfh[f] = *(const bf16x8*)&lds[2][ib];
      bfl[f] = *(const bf16x8*)&lds[3][ib];
    }
#pragma unroll
    for (int i = 0; i < 4; ++i)
#pragma unroll
      for (int j = 0; j < 4; ++j) {
        acc[i][j] = MFB(afh[i], bfh[j], acc[i][j]);
        acc[i][j] = MFB(afh[i], bfl[j], acc[i][j]);
        acc[i][j] = MFB(afl[i], bfh[j], acc[i][j]);
      }
    __syncthreads();
  }

  // epilogue: C/D layout col = lane&15, row = (lane>>4)*4 + reg
#pragma unroll
  for (int i = 0; i < 4; ++i)
#pragma unroll
    for (int j = 0; j < 4; ++j)
#pragma unroll
      for (int r = 0; r < 4; ++r) {
        int m = m0 + wm * 64 + i * 16 + kg * 4 + r;
        int nn = n0 + wn * 64 + j * 16 + r15;
        float v = acc[i][j][r];
        if (MODE == 0) {           // c@Wkv -> Kh/Kl [B,N,T,64], VT f16 [B,N,64,T]
          int tt = m >> 2, bb = m & 3;
          if (nn < 1024) {
            int hn = nn >> 6, d = nn & 63;
            size_t idx = ((size_t)(bb * 16 + hn) * 2048 + tt) * 64 + d;
            unsigned short hi = bf16rn(v);
            p0[idx] = hi; p1[idx] = bf16rn(v - bf16tof(hi));
          } else {
            int c2 = nn - 1024, hn = c2 >> 6, d = c2 & 63;
            union { _Float16 h; unsigned short u; } cv; cv.h = (_Float16)v;
            p2[((size_t)(bb * 16 + hn) * 64 + d) * 2048 + tt] = cv.u;
          }
        } else if (MODE == 1) {    // x@Wq + biases -> Quh/Qul/Qvh/Qvl [B,N,I,64]
          int i2 = m >> 2, bb = m & 3;
          int hn = nn >> 6, d = nn & 63;
          size_t idx = ((size_t)(bb * 16 + hn) * 1024 + i2) * 64 + d;
          float vu = v + e0[nn], vv = v + e1[nn];
          unsigned short h0 = bf16rn(vu);
          p0[idx] = h0; p1[idx] = bf16rn(vu - bf16tof(h0));
          unsigned short h1 = bf16rn(vv);
          p2[idx] = h1; p3[idx] = bf16rn(vv - bf16tof(h1));
        } else if (MODE == 2) {    // pos@Wrel -> Rh/Rl [B,N,T,64]
          int tt = m >> 2, bb = m & 3;
          int hn = nn >> 6, d = nn & 63;
          size_t idx = ((size_t)(bb * 16 + hn) * 2048 + tt) * 64 + d;
          unsigned short hi = bf16rn(v);
          p0[idx] = hi; p1[idx] = bf16rn(v - bf16tof(hi));
        } else if (MODE == 3) {    // vec@Wo + x -> t1 (fp32)
          o0[(size_t)m * N + nn] = v + e0[(size_t)m * N + nn];
        } else if (MODE == 4) {    // relu(h@W1 + b1) -> ffp hi/lo bf16
          float v2 = fmaxf(v + e0[nn], 0.f);
          unsigned short hh = bf16rn(v2);
          p0[(size_t)m * N + nn] = hh;
          p1[(size_t)m * N + nn] = bf16rn(v2 - bf16tof(hh));
        } else if (MODE == 5) {    // ff@W2 + b2 + h -> t2 (fp32)
          o0[(size_t)m * N + nn] = v + e0[nn] + e1[(size_t)m * N + nn];
        }
      }
}

// ---------------- MFMA attention ----------------
// block = (16 q-rows, b, 8-head group); 8 waves; swapped-operand S^T so each
// lane holds one q-row's 64 scores in regs. D (rel-pos) via MFMA into f16 LDS
// window; exact per-row fp32 softmax; PV via f16 MFMA. P head-sum accumulated
// in packed-f16 registers, stored ONCE per block (no atomics).
// __launch_bounds__(512, 2): round-6 lesson — (512,4) capped VGPR at 128 while
// peak live set is ~150 (sa[16] f32x4 = 64 alone) -> ~90 regs spilled to
// scratch, 4 GB/dispatch of spill traffic (VGPR_Count=64, WRITE_SIZE 2.2 GB).
// Cap 256 VGPR trades occupancy (1 blk/CU) for zero spill.
__global__ __launch_bounds__(512, 2) void attn_k(
    const unsigned short* __restrict__ Kh, const unsigned short* __restrict__ Kl,
    const unsigned short* __restrict__ Rh, const unsigned short* __restrict__ Rl,
    const unsigned short* __restrict__ Quh, const unsigned short* __restrict__ Qul,
    const unsigned short* __restrict__ Qvh, const unsigned short* __restrict__ Qvl,
    const _Float16* __restrict__ VT,
    float* __restrict__ vec, float* __restrict__ acc0, float* __restrict__ acc1)
{
  __shared__ _Float16 Dl[16][2072];            // D window, then normalized P
  __shared__ unsigned short qs[4][8][16][8];   // Q^T frags: arr, dchunk, i, e
  __shared__ float red[2][8][16];
  const int t = threadIdx.x, wave = t >> 6, lane = t & 63;
  const int g = lane >> 4, i15 = lane & 15;
  const int i0 = blockIdx.x * 16, b = blockIdx.y;
  const int jr0 = 1008 - i0;
  const int NS = (2048 - jr0) >> 4;
  const int jb = wave * 256;

  f16x4 pacc[16];
#pragma unroll
  for (int js = 0; js < 16; ++js) pacc[js] = (f16x4){};

  for (int hh = 0; hh < 8; ++hh) {
    const int n = blockIdx.z * 8 + hh;
    const size_t bn = (size_t)(b * 16 + n);

    {  // stage Q^T tiles (transpose into frag-ready layout)
      int a = t & 127, arr = t >> 7;
      const unsigned short* sp = arr == 0 ? Quh : arr == 1 ? Qul
                               : arr == 2 ? Qvh : Qvl;
      *(uint4*)&qs[arr][a >> 4][a & 15][0] =
          *(const uint4*)&sp[((bn << 10) + i0 + (a & 15)) * 64 + (a >> 4) * 8];
    }
    __syncthreads();

    // ---- D^T phase: D[jr][i] = R[jr]·Qv[i], subtiles round-robin over waves
    for (int s = wave; s < NS; s += 8) {
      const size_t kb = (bn * 2048 + (jr0 + s * 16 + i15)) * 64 + g * 8;
      bf16x8 rh0 = *(const bf16x8*)&Rh[kb];
      bf16x8 rh1 = *(const bf16x8*)&Rh[kb + 32];
      bf16x8 rl0 = *(const bf16x8*)&Rl[kb];
      bf16x8 rl1 = *(const bf16x8*)&Rl[kb + 32];
      bf16x8 vh0 = *(const bf16x8*)&qs[2][g][i15][0];
      bf16x8 vh1 = *(const bf16x8*)&qs[2][4 + g][i15][0];
      bf16x8 vl0 = *(const bf16x8*)&qs[3][g][i15][0];
      bf16x8 vl1 = *(const bf16x8*)&qs[3][4 + g][i15][0];
      f32x4 acc = {};
      acc = MFB(rh0, vh0, acc); acc = MFB(rh1, vh1, acc);
      acc = MFB(rh0, vl0, acc); acc = MFB(rh1, vl1, acc);
      acc = MFB(rl0, vh0, acc); acc = MFB(rl1, vh1, acc);
#pragma unroll
      for (int r = 0; r < 4; ++r)
        Dl[i15][s * 16 + g * 4 + r] = (_Float16)acc[r];
    }
    __syncthreads();

    // ---- AC phase: S^T = K·Qu over this wave's 256-j slab
    f32x4 sa[16];
#pragma unroll
    for (int js = 0; js < 16; ++js) sa[js] = (f32x4){};
    {
      bf16x8 uh0 = *(const bf16x8*)&qs[0][g][i15][0];
      bf16x8 uh1 = *(const bf16x8*)&qs[0][4 + g][i15][0];
      bf16x8 ul0 = *(const bf16x8*)&qs[1][g][i15][0];
      bf16x8 ul1 = *(const bf16x8*)&qs[1][4 + g][i15][0];
#pragma unroll 2
      for (int js = 0; js < 16; ++js) {
        const size_t kb = (bn * 2048 + (jb + js * 16 + i15)) * 64 + g * 8;
        bf16x8 kh0 = *(const bf16x8*)&Kh[kb];
        bf16x8 kh1 = *(const bf16x8*)&Kh[kb + 32];
        bf16x8 kl0 = *(const bf16x8*)&Kl[kb];
        bf16x8 kl1 = *(const bf16x8*)&Kl[kb + 32];
        f32x4 a = sa[js];
        a = MFB(kh0, uh0, a); a = MFB(kh1, uh1, a);
        a = MFB(kh0, ul0, a); a = MFB(kh1, ul1, a);
        a = MFB(kl0, uh0, a); a = MFB(kl1, uh1, a);
        sa[js] = a;
      }
    }

    // ---- combine shifted D + mask + scale; per-row max
    float m = -1e30f;
#pragma unroll
    for (int js = 0; js < 16; ++js)
#pragma unroll
      for (int r = 0; r < 4; ++r) {
        int j = jb + js * 16 + g * 4 + r;
        float sv = (sa[js][r] + (float)Dl[i15][j + 15 - i15]) * 0.125f;
        sv = (j <= i0 + i15 + 1024) ? sv : -1e30f;
        sa[js][r] = sv;
        m = fmaxf(m, sv);
      }
    m = fmaxf(m, __shfl_xor(m, 16));
    m = fmaxf(m, __shfl_xor(m, 32));
    if (g == 0) red[0][wave][i15] = m;
    __syncthreads();           // (a) combines done -> Dl reusable; maxes in
    float mi = red[0][0][i15];
#pragma unroll
    for (int w = 1; w < 8; ++w) mi = fmaxf(mi, red[0][w][i15]);
    float l = 0.f;
#pragma unroll
    for (int js = 0; js < 16; ++js)
#pragma unroll
      for (int r = 0; r < 4; ++r) {
        float p = __expf(sa[js][r] - mi);
        sa[js][r] = p; l += p;
      }
    l += __shfl_xor(l, 16);
    l += __shfl_xor(l, 32);
    if (g == 0) red[1][wave][i15] = l;
    __syncthreads();           // (b) sums in
    float li = 0.f;
#pragma unroll
    for (int w = 0; w < 8; ++w) li += red[1][w][i15];
    float rinv = 1.f / li;
#pragma unroll
    for (int js = 0; js < 16; ++js) {
      f16x4 pk;
#pragma unroll
      for (int r = 0; r < 4; ++r) pk[r] = (_Float16)(sa[js][r] * rinv);
      *(f16x4*)&Dl[i15][jb + js * 16 + g * 4] = pk;
      pacc[js] += pk;          // head-sum accumulation in registers
    }
    __syncthreads();           // (c) P ready

    // ---- PV: vec_partial = P·V over this wave's slab (f16 MFMA)
    f32x4 va[4];
#pragma unroll
    for (int d = 0; d < 4; ++d) va[d] = (f32x4){};
#pragma unroll 2
    for (int kc = 0; kc < 8; ++kc) {
      f16x8 pa = *(const f16x8*)&Dl[i15][jb + kc * 32 + g * 8];
#pragma unroll
      for (int d = 0; d < 4; ++d) {
        f16x8 vb = *(const f16x8*)&VT[(bn * 64 + d * 16 + i15) * 2048 + jb + kc * 32 + g * 8];
        va[d] = MFH(pa, vb, va[d]);
      }
    }
    __syncthreads();           // (d) all P reads done -> Dl as fp32 scratch
    float* sc2 = (float*)&Dl[0][0];
#pragma unroll
    for (int d = 0; d < 4; ++d)
#pragma unroll
      for (int r = 0; r < 4; ++r)
        sc2[(wave * 16 + g * 4 + r) * 64 + d * 16 + i15] = va[d][r];
    __syncthreads();           // (e) partials staged
    {
      int ii = t >> 5, dp = (t & 31) * 2;
      float s0 = 0.f, s1 = 0.f;
#pragma unroll
      for (int w = 0; w < 8; ++w) {
        s0 += sc2[(w * 16 + ii) * 64 + dp];
        s1 += sc2[(w * 16 + ii) * 64 + dp + 1];
      }
      float* vp = &vec[(((size_t)(i0 + ii) * 4 + b) << 10) + n * 64 + dp];
      vp[0] = s0; vp[1] = s1;
    }
    __syncthreads();           // (f) scratch/qs free for next head
  }

  // ---- write head-summed P once (block-exclusive region, no atomics)
  {
    float* ap = blockIdx.z ? acc1 : acc0;
    float* rp = &ap[((size_t)b * 1024 + i0 + i15) * 2048];
#pragma unroll
    for (int js = 0; js < 16; ++js) {
      float4 o;
      o.x = (float)pacc[js][0]; o.y = (float)pacc[js][1];
      o.z = (float)pacc[js][2]; o.w = (float)pacc[js][3];
      *(float4*)&rp[jb + js * 16 + g * 4] = o;
    }
  }
}

// ---------------- attn matrix finalize: mean over batch + z-halves ----------
__global__ __launch_bounds__(256) void attnfin_k(const float* __restrict__ a0,
                                                 const float* __restrict__ a1,
                                                 float* __restrict__ out)
{
  size_t idx = (size_t)blockIdx.x * 256 + threadIdx.x;
  const size_t S = (size_t)XLEN * TOT;
  float s = 0.f;
#pragma unroll
  for (int b = 0; b < 4; ++b) s += a0[idx + b * S] + a1[idx + b * S];
  out[idx] = s * (1.0f / 64.0f);
}

// ---------------- LayerNorm (+optional bf16 hi/lo split output) -------------
template<int SPLIT>
__global__ __launch_bounds__(256) void ln_k(const float* __restrict__ in,
                                            const float* __restrict__ g,
                                            const float* __restrict__ bb,
                                            float* __restrict__ out,
                                            unsigned short* __restrict__ oh,
                                            unsigned short* __restrict__ ol)
{
  __shared__ float rbuf[8];
  const int row = blockIdx.x;
  const int t = threadIdx.x;
  const float* p = in + (size_t)row * DM;
  float4 v = *(const float4*)(p + t * 4);
  float s1 = v.x + v.y + v.z + v.w;
  float s2 = v.x * v.x + v.y * v.y + v.z * v.z + v.w * v.w;
#pragma unroll
  for (int off = 32; off; off >>= 1) {
    s1 += __shfl_xor(s1, off);
    s2 += __shfl_xor(s2, off);
  }
  const int wv = t >> 6, lane = t & 63;
  if (lane == 0) { rbuf[wv] = s1; rbuf[4 + wv] = s2; }
  __syncthreads();
  if (t == 0) {
    float a = rbuf[0] + rbuf[1] + rbuf[2] + rbuf[3];
    float b2 = rbuf[4] + rbuf[5] + rbuf[6] + rbuf[7];
    float mu = a * (1.f / DM);
    float var = b2 * (1.f / DM) - mu * mu;
    rbuf[0] = mu;
    rbuf[1] = rsqrtf(var + 1e-5f);
  }
  __syncthreads();
  float mu = rbuf[0], rs = rbuf[1];
  float4 gv = *(const float4*)(g + t * 4);
  float4 bv = *(const float4*)(bb + t * 4);
  float4 o;
  o.x = (v.x - mu) * rs * gv.x + bv.x;
  o.y = (v.y - mu) * rs * gv.y + bv.y;
  o.z = (v.z - mu) * rs * gv.z + bv.z;
  o.w = (v.w - mu) * rs * gv.w + bv.w;
  *(float4*)(out + (size_t)row * DM + t * 4) = o;
  if (SPLIT) {
    ushort4 h, l;
    h.x = bf16rn(o.x); l.x = bf16rn(o.x - bf16tof(h.x));
    h.y = bf16rn(o.y); l.y = bf16rn(o.y - bf16tof(h.y));
    h.z = bf16rn(o.z); l.z = bf16rn(o.z - bf16tof(h.z));
    h.w = bf16rn(o.w); l.w = bf16rn(o.w - bf16tof(h.w));
    *(ushort4*)(oh + (size_t)row * DM + t * 4) = h;
    *(ushort4*)(ol + (size_t)row * DM + t * 4) = l;
  }
}

// ---------------- launch ----------------
extern "C" void kernel_launch(void* const* d_in, const int* in_sizes, int n_in,
                              void* d_out, int out_size, void* d_ws, size_t ws_size,
                              hipStream_t stream) {
  const float* x      = (const float*)d_in[0];
  const float* memory = (const float*)d_in[1];
  const float* pos    = (const float*)d_in[2];
  const float* pbu    = (const float*)d_in[3];
  const float* pbv    = (const float*)d_in[4];
  const float* Wq   = (const float*)d_in[6];
  const float* Wkv  = (const float*)d_in[7];
  const float* Wrel = (const float*)d_in[8];
  const float* Wo   = (const float*)d_in[9];
  const float* ln1g = (const float*)d_in[10];
  const float* ln1b = (const float*)d_in[11];
  const float* W1   = (const float*)d_in[12];
  const float* b1   = (const float*)d_in[13];
  const float* W2   = (const float*)d_in[14];
  const float* b2   = (const float*)d_in[15];
  const float* ln2g = (const float*)d_in[16];
  const float* ln2b = (const float*)d_in[17];

  float* out   = (float*)d_out;                    // [1024,4,1024]
  float* attnm = out + (size_t)XLEN * BATCH * DM;  // [1024,2048]
  float* ws = (float*)d_ws;
  const size_t M1 = 1048576;  // 1M floats

  // ---- workspace (offsets in floats; bf16/f16 arrays cast) ----
  unsigned short* c_h   = (unsigned short*)(ws + 0);          // [0,4M)
  unsigned short* c_l   = (unsigned short*)(ws + 4 * M1);     // [4,8M)
  float* pos_f[2] = { ws + 8 * M1, ws + 12 * M1 };            // [8,16M)
  unsigned short* pos_h = (unsigned short*)pos_f[0];
  unsigned short* pos_l = (unsigned short*)pos_f[1];
  unsigned short* Wkvh  = (unsigned short*)(ws + 16 * M1);
  unsigned short* Wkvl  = (unsigned short*)(ws + 17 * M1);
  unsigned short* Wqh   = (unsigned short*)(ws + 18 * M1);
  unsigned short* Wql   = (unsigned short*)(ws + 18 * M1 + M1 / 2);
  unsigned short* Wrelh = (unsigned short*)(ws + 19 * M1);
  unsigned short* Wrell = (unsigned short*)(ws + 19 * M1 + M1 / 2);
  unsigned short* Rh    = (unsigned short*)(ws + 20 * M1);    // [20,24M)
  unsigned short* Rl    = (unsigned short*)(ws + 24 * M1);    // [24,28M)
  unsigned short* Quh   = (unsigned short*)(ws + 28 * M1);    // [28,30M)
  unsigned short* Qul   = (unsigned short*)(ws + 30 * M1);
  unsigned short* Qvh   = (unsigned short*)(ws + 32 * M1);
  unsigned short* Qvl   = (unsigned short*)(ws + 34 * M1);
  unsigned short* Kh    = (unsigned short*)(ws + 8 * M1);     // over pos
  unsigned short* Kl    = (unsigned short*)(ws + 12 * M1);
  unsigned short* VTu   = (unsigned short*)(ws + 36 * M1);    // [36,40M) f16
  float* attnacc0       = ws + 0;                              // over c [0,8M)
  float* attnacc1       = ws + 44 * M1;                        // [44,52M)
  float* vec            = ws + 16 * M1;                        // over W splits
  // post-attention
  unsigned short* vech  = (unsigned short*)(ws + 8 * M1);     // over Kh
  unsigned short* vecl  = (unsigned short*)(ws + 10 * M1);
  unsigned short* W1h   = (unsigned short*)(ws + 12 * M1);    // over Kl
  unsigned short* W1l   = (unsigned short*)(ws + 14 * M1);
  unsigned short* W2h   = (unsigned short*)(ws + 0);          // over attnacc0
  unsigned short* W2l   = (unsigned short*)(ws + 2 * M1);
  unsigned short* Woh   = (unsigned short*)(ws + 4 * M1);
  unsigned short* Wol   = (unsigned short*)(ws + 4 * M1 + M1 / 2);
  float* t1             = ws + 40 * M1;                        // [40,44M)
  float* h              = ws + 16 * M1;                        // over vec
  unsigned short* hhp   = (unsigned short*)(ws + 20 * M1);    // over Rh
  unsigned short* hlp   = (unsigned short*)(ws + 22 * M1);
  unsigned short* ffph  = (unsigned short*)(ws + 24 * M1);    // [24,32M)
  unsigned short* ffpl  = (unsigned short*)(ws + 32 * M1);    // [32,40M)
  float* t2             = ws + 8 * M1;                         // over vech/vecl

  // 1) pre-attention splits
  split2_k<<<8192, 256, 0, stream>>>(memory, x, MEMLEN * BATCH * DM, c_h, c_l);
  split2_k<<<8192, 256, 0, stream>>>(pos, pos, 1 << 30, pos_h, pos_l);
  tsplit_k<<<dim3(16, 32), 256, 0, stream>>>(Wkv, DM, 2048, Wkvh, Wkvl);
  tsplit_k<<<dim3(16, 16), 256, 0, stream>>>(Wq, DM, 1024, Wqh, Wql);
  tsplit_k<<<dim3(16, 16), 256, 0, stream>>>(Wrel, DM, 1024, Wrelh, Wrell);

  // 2) R = pos@Wrel (pos dead after)
  gemm_k<2><<<dim3(8, 64), 256, 0, stream>>>(pos_h, pos_l, Wrelh, Wrell, 1024, DM,
      nullptr, nullptr, nullptr, Rh, Rl, nullptr, nullptr);
  // 3) Qu,Qv = x@Wq (+biases)
  gemm_k<1><<<dim3(8, 32), 256, 0, stream>>>(c_h + 4194304, c_l + 4194304, Wqh, Wql,
      1024, DM, pbu, pbv, nullptr, Quh, Qul, Qvh, Qvl);
  // 4) K,VT = c@Wkv (K overwrites pos region; c dead after)
  gemm_k<0><<<dim3(16, 64), 256, 0, stream>>>(c_h, c_l, Wkvh, Wkvl, 2048, DM,
      nullptr, nullptr, nullptr, Kh, Kl, VTu, nullptr);
  // 5) attention (P head-sums written exclusively; no zeroing needed)
  attn_k<<<dim3(64, 4, 2), 512, 0, stream>>>(Kh, Kl, Rh, Rl, Quh, Qul, Qvh, Qvl,
      (const _Float16*)VTu, vec, attnacc0, attnacc1);
  // 6) attn matrix mean over batch
  attnfin_k<<<(XLEN * TOT) / 256, 256, 0, stream>>>(attnacc0, attnacc1, attnm);

  // 7) post-attention splits
  split2_k<<<4096, 256, 0, stream>>>(vec, vec, 1 << 30, vech, vecl);
  tsplit_k<<<dim3(16, 64), 256, 0, stream>>>(W1, DM, DFF, W1h, W1l);
  tsplit_k<<<dim3(64, 16), 256, 0, stream>>>(W2, DFF, 1024, W2h, W2l);
  tsplit_k<<<dim3(16, 16), 256, 0, stream>>>(Wo, DM, 1024, Woh, Wol);

  // 8) attn_out = vec@Wo + x -> t1
  gemm_k<3><<<dim3(8, 32), 256, 0, stream>>>(vech, vecl, Woh, Wol, 1024, DM,
      x, nullptr, t1, nullptr, nullptr, nullptr, nullptr);
  // 9) h = LN1(t1) + bf16 hi/lo
  ln_k<1><<<XLEN * BATCH, 256, 0, stream>>>(t1, ln1g, ln1b, h, hhp, hlp);
  // 10) ffp = relu(h@W1 + b1) bf16 hi/lo
  gemm_k<4><<<dim3(32, 32), 256, 0, stream>>>(hhp, hlp, W1h, W1l, DFF, DM,
      b1, nullptr, nullptr, ffph, ffpl, nullptr, nullptr);
  // 11) t2 = ffp@W2 + b2 + h
  gemm_k<5><<<dim3(8, 32), 256, 0, stream>>>(ffph, ffpl, W2h, W2l, 1024, DFF,
      b2, h, t2, nullptr, nullptr, nullptr, nullptr);
  // 12) out = LN2(t2)
  ln_k<0><<<XLEN * BATCH, 256, 0, stream>>>(t2, ln2g, ln2b, out, nullptr, nullptr);
}

// Round 8
// 1853.304 us; speedup vs baseline: 3.9565x; 1.0032x over previous
//
#include <hip/hip_runtime.h>

#define NHEAD 16
#define DHEAD 64
#define XLEN 1024
#define MEMLEN 1024
#define BATCH 4
#define TOT 2048
#define DFF 4096
#define DM 1024

typedef __attribute__((ext_vector_type(8))) short bf16x8;
typedef __attribute__((ext_vector_type(4))) float f32x4;
typedef __attribute__((ext_vector_type(8))) _Float16 f16x8;
typedef __attribute__((ext_vector_type(4))) _Float16 f16x4;

#define MFB(A, B, C) __builtin_amdgcn_mfma_f32_16x16x32_bf16(A, B, C, 0, 0, 0)
#define MFH(A, B, C) __builtin_amdgcn_mfma_f32_16x16x32_f16(A, B, C, 0, 0, 0)

__device__ __forceinline__ unsigned short bf16rn(float x) {
  union { float f; unsigned u; } c{x};
  unsigned r = c.u + 0x7fffu + ((c.u >> 16) & 1u);
  return (unsigned short)(r >> 16);
}
__device__ __forceinline__ float bf16tof(unsigned short h) {
  union { unsigned u; float f; } c{(unsigned)h << 16};
  return c.f;
}

#define GLOAD_LDS16(gp, lp)                                                    \
  __builtin_amdgcn_global_load_lds(                                            \
      (const __attribute__((address_space(1))) unsigned int*)(gp),             \
      (__attribute__((address_space(3))) unsigned int*)(lp), 16, 0, 0)

// ---------------- elementwise split: fp32 -> bf16 hi + bf16 lo --------------
__global__ __launch_bounds__(256) void split2_k(
    const float* __restrict__ s0, const float* __restrict__ s1, int splitElems,
    unsigned short* __restrict__ oh, unsigned short* __restrict__ ol)
{
  int i4 = (blockIdx.x * 256 + threadIdx.x) * 4;
  const float* src = (i4 < splitElems) ? (s0 + i4) : (s1 + (i4 - splitElems));
  float4 v = *(const float4*)src;
  ushort4 h, l;
  h.x = bf16rn(v.x); l.x = bf16rn(v.x - bf16tof(h.x));
  h.y = bf16rn(v.y); l.y = bf16rn(v.y - bf16tof(h.y));
  h.z = bf16rn(v.z); l.z = bf16rn(v.z - bf16tof(h.z));
  h.w = bf16rn(v.w); l.w = bf16rn(v.w - bf16tof(h.w));
  *(ushort4*)(oh + i4) = h;
  *(ushort4*)(ol + i4) = l;
}

// ------------- transpose + split: W[K][N] fp32 -> Wt hi/lo [N][K] bf16 ------
__global__ __launch_bounds__(256) void tsplit_k(
    const float* __restrict__ W, int K, int N,
    unsigned short* __restrict__ oh, unsigned short* __restrict__ ol)
{
  __shared__ float tile[64][65];
  const int t = threadIdx.x;
  const int bk = blockIdx.x * 64, bn = blockIdx.y * 64;
#pragma unroll
  for (int r = 0; r < 4; ++r) {
    int lr = r * 16 + (t >> 4), lc = (t & 15) * 4;
    *(float4*)&tile[lr][lc] = *(const float4*)&W[(size_t)(bk + lr) * N + bn + lc];
  }
  __syncthreads();
  const int n = t >> 2, kq = t & 3;
  unsigned short* ph = oh + (size_t)(bn + n) * K + bk + kq * 16;
  unsigned short* pl = ol + (size_t)(bn + n) * K + bk + kq * 16;
#pragma unroll
  for (int c = 0; c < 4; ++c) {
    ushort4 h, l;
    float v0 = tile[kq * 16 + c * 4 + 0][n];
    float v1 = tile[kq * 16 + c * 4 + 1][n];
    float v2 = tile[kq * 16 + c * 4 + 2][n];
    float v3 = tile[kq * 16 + c * 4 + 3][n];
    h.x = bf16rn(v0); l.x = bf16rn(v0 - bf16tof(h.x));
    h.y = bf16rn(v1); l.y = bf16rn(v1 - bf16tof(h.y));
    h.z = bf16rn(v2); l.z = bf16rn(v2 - bf16tof(h.z));
    h.w = bf16rn(v3); l.w = bf16rn(v3 - bf16tof(h.w));
    *(ushort4*)(ph + c * 4) = h;
    *(ushort4*)(pl + c * 4) = l;
  }
}

// ---------------- MFMA GEMM: 128x128 tile, 3-term Markidis ------------------
template<int MODE>
__global__ __launch_bounds__(256) void gemm_k(
    const unsigned short* __restrict__ Ah, const unsigned short* __restrict__ Al,
    const unsigned short* __restrict__ Bh, const unsigned short* __restrict__ Bl,
    int N, int K,
    const float* __restrict__ e0, const float* __restrict__ e1,
    float* __restrict__ o0,
    unsigned short* __restrict__ p0, unsigned short* __restrict__ p1,
    unsigned short* __restrict__ p2, unsigned short* __restrict__ p3)
{
  __shared__ unsigned short lds[4][4096];  // Ah,Al,Bh,Bl: 128 rows x 32 bf16
  const int t = threadIdx.x;
  const int wave = t >> 6, lane = t & 63;
  const int wm = wave >> 1, wn = wave & 1;
  const int m0 = blockIdx.y * 128, n0 = blockIdx.x * 128;

  const unsigned short* gp[2][4];
  unsigned short* lp[2][4];
#pragma unroll
  for (int i = 0; i < 2; ++i) {
    int s = i * 256 + t, row = s >> 2, sl = s & 3;
    int csw = (sl ^ (row & 3)) * 8;
    gp[i][0] = Ah + (size_t)(m0 + row) * K + csw;
    gp[i][1] = Al + (size_t)(m0 + row) * K + csw;
    gp[i][2] = Bh + (size_t)(n0 + row) * K + csw;
    gp[i][3] = Bl + (size_t)(n0 + row) * K + csw;
#pragma unroll
    for (int a = 0; a < 4; ++a) lp[i][a] = &lds[a][s * 8];
  }

  f32x4 acc[4][4] = {};
  const int kg = lane >> 4, r15 = lane & 15;

  for (int k0 = 0; k0 < K; k0 += 32) {
#pragma unroll
    for (int i = 0; i < 2; ++i)
#pragma unroll
      for (int a = 0; a < 4; ++a) GLOAD_LDS16(gp[i][a] + k0, lp[i][a]);
    __syncthreads();

    bf16x8 afh[4], afl[4], bfh[4], bfl[4];
#pragma unroll
    for (int f = 0; f < 4; ++f) {
      int rowA = wm * 64 + f * 16 + r15;
      int ia = (rowA * 4 + (kg ^ (rowA & 3))) * 8;
      afh[f] = *(const bf16x8*)&lds[0][ia];
      afl[f] = *(const bf16x8*)&lds[1][ia];
      int rowB = wn * 64 + f * 16 + r15;
      int ib = (rowB * 4 + (kg ^ (rowB & 3))) * 8;
      bfh[f] = *(const bf16x8*)&lds[2][ib];
      bfl[f] = *(const bf16x8*)&lds[3][ib];
    }
#pragma unroll
    for (int i = 0; i < 4; ++i)
#pragma unroll
      for (int j = 0; j < 4; ++j) {
        acc[i][j] = MFB(afh[i], bfh[j], acc[i][j]);
        acc[i][j] = MFB(afh[i], bfl[j], acc[i][j]);
        acc[i][j] = MFB(afl[i], bfh[j], acc[i][j]);
      }
    __syncthreads();
  }

  // epilogue: C/D layout col = lane&15, row = (lane>>4)*4 + reg
#pragma unroll
  for (int i = 0; i < 4; ++i)
#pragma unroll
    for (int j = 0; j < 4; ++j)
#pragma unroll
      for (int r = 0; r < 4; ++r) {
        int m = m0 + wm * 64 + i * 16 + kg * 4 + r;
        int nn = n0 + wn * 64 + j * 16 + r15;
        float v = acc[i][j][r];
        if (MODE == 0) {           // c@Wkv -> Kh/Kl [B,N,T,64], VT f16 [B,N,64,T]
          int tt = m >> 2, bb = m & 3;
          if (nn < 1024) {
            int hn = nn >> 6, d = nn & 63;
            size_t idx = ((size_t)(bb * 16 + hn) * 2048 + tt) * 64 + d;
            unsigned short hi = bf16rn(v);
            p0[idx] = hi; p1[idx] = bf16rn(v - bf16tof(hi));
          } else {
            int c2 = nn - 1024, hn = c2 >> 6, d = c2 & 63;
            union { _Float16 h; unsigned short u; } cv; cv.h = (_Float16)v;
            p2[((size_t)(bb * 16 + hn) * 64 + d) * 2048 + tt] = cv.u;
          }
        } else if (MODE == 1) {    // x@Wq + biases -> Quh/Qul/Qvh/Qvl [B,N,I,64]
          int i2 = m >> 2, bb = m & 3;
          int hn = nn >> 6, d = nn & 63;
          size_t idx = ((size_t)(bb * 16 + hn) * 1024 + i2) * 64 + d;
          float vu = v + e0[nn], vv = v + e1[nn];
          unsigned short h0 = bf16rn(vu);
          p0[idx] = h0; p1[idx] = bf16rn(vu - bf16tof(h0));
          unsigned short h1 = bf16rn(vv);
          p2[idx] = h1; p3[idx] = bf16rn(vv - bf16tof(h1));
        } else if (MODE == 2) {    // pos@Wrel -> Rh/Rl [B,N,T,64]
          int tt = m >> 2, bb = m & 3;
          int hn = nn >> 6, d = nn & 63;
          size_t idx = ((size_t)(bb * 16 + hn) * 2048 + tt) * 64 + d;
          unsigned short hi = bf16rn(v);
          p0[idx] = hi; p1[idx] = bf16rn(v - bf16tof(hi));
        } else if (MODE == 3) {    // vec@Wo + x -> t1 (fp32)
          o0[(size_t)m * N + nn] = v + e0[(size_t)m * N + nn];
        } else if (MODE == 4) {    // relu(h@W1 + b1) -> ffp hi/lo bf16
          float v2 = fmaxf(v + e0[nn], 0.f);
          unsigned short hh = bf16rn(v2);
          p0[(size_t)m * N + nn] = hh;
          p1[(size_t)m * N + nn] = bf16rn(v2 - bf16tof(hh));
        } else if (MODE == 5) {    // ff@W2 + b2 + h -> t2 (fp32)
          o0[(size_t)m * N + nn] = v + e0[nn] + e1[(size_t)m * N + nn];
        }
      }
}

// ---------------- MFMA attention ----------------
// block = (16 q-rows, b, 8-head group); 8 waves; swapped-operand S^T so each
// lane holds one q-row's 64 scores in regs. D (rel-pos) via MFMA into f16 LDS
// window; exact per-row fp32 softmax; PV via f16 MFMA. P head-sum in packed-f16
// registers, stored ONCE per block (no atomics).
// amdgpu_waves_per_eu(2,2): rounds 6/7 lesson — __launch_bounds__ 2nd arg only
// CAPS VGPR (min waves/EU); the memory-bound heuristic still targeted max
// occupancy and spilled ~60 regs (VGPR=64/92, ~2.1 GB scratch writes/dispatch).
// Setting max waves/EU = 2 makes >2 waves impossible, so the allocator keeps
// the full ~150-reg live set in registers (cap 256) with zero spill.
__global__ __launch_bounds__(512)
__attribute__((amdgpu_waves_per_eu(2, 2))) void attn_k(
    const unsigned short* __restrict__ Kh, const unsigned short* __restrict__ Kl,
    const unsigned short* __restrict__ Rh, const unsigned short* __restrict__ Rl,
    const unsigned short* __restrict__ Quh, const unsigned short* __restrict__ Qul,
    const unsigned short* __restrict__ Qvh, const unsigned short* __restrict__ Qvl,
    const _Float16* __restrict__ VT,
    float* __restrict__ vec, float* __restrict__ acc0, float* __restrict__ acc1)
{
  __shared__ _Float16 Dl[16][2072];            // D window, then normalized P
  __shared__ unsigned short qs[4][8][16][8];   // Q^T frags: arr, dchunk, i, e
  __shared__ float red[2][8][16];
  const int t = threadIdx.x, wave = t >> 6, lane = t & 63;
  const int g = lane >> 4, i15 = lane & 15;
  const int i0 = blockIdx.x * 16, b = blockIdx.y;
  const int jr0 = 1008 - i0;
  const int NS = (2048 - jr0) >> 4;
  const int jb = wave * 256;

  f16x4 pacc[16];
#pragma unroll
  for (int js = 0; js < 16; ++js) pacc[js] = (f16x4){};

  for (int hh = 0; hh < 8; ++hh) {
    const int n = blockIdx.z * 8 + hh;
    const size_t bn = (size_t)(b * 16 + n);

    {  // stage Q^T tiles (transpose into frag-ready layout)
      int a = t & 127, arr = t >> 7;
      const unsigned short* sp = arr == 0 ? Quh : arr == 1 ? Qul
                               : arr == 2 ? Qvh : Qvl;
      *(uint4*)&qs[arr][a >> 4][a & 15][0] =
          *(const uint4*)&sp[((bn << 10) + i0 + (a & 15)) * 64 + (a >> 4) * 8];
    }
    __syncthreads();

    // ---- D^T phase: D[jr][i] = R[jr]·Qv[i], subtiles round-robin over waves
    for (int s = wave; s < NS; s += 8) {
      const size_t kb = (bn * 2048 + (jr0 + s * 16 + i15)) * 64 + g * 8;
      bf16x8 rh0 = *(const bf16x8*)&Rh[kb];
      bf16x8 rh1 = *(const bf16x8*)&Rh[kb + 32];
      bf16x8 rl0 = *(const bf16x8*)&Rl[kb];
      bf16x8 rl1 = *(const bf16x8*)&Rl[kb + 32];
      bf16x8 vh0 = *(const bf16x8*)&qs[2][g][i15][0];
      bf16x8 vh1 = *(const bf16x8*)&qs[2][4 + g][i15][0];
      bf16x8 vl0 = *(const bf16x8*)&qs[3][g][i15][0];
      bf16x8 vl1 = *(const bf16x8*)&qs[3][4 + g][i15][0];
      f32x4 acc = {};
      acc = MFB(rh0, vh0, acc); acc = MFB(rh1, vh1, acc);
      acc = MFB(rh0, vl0, acc); acc = MFB(rh1, vl1, acc);
      acc = MFB(rl0, vh0, acc); acc = MFB(rl1, vh1, acc);
#pragma unroll
      for (int r = 0; r < 4; ++r)
        Dl[i15][s * 16 + g * 4 + r] = (_Float16)acc[r];
    }
    __syncthreads();

    // ---- AC phase: S^T = K·Qu over this wave's 256-j slab
    f32x4 sa[16];
#pragma unroll
    for (int js = 0; js < 16; ++js) sa[js] = (f32x4){};
    {
      bf16x8 uh0 = *(const bf16x8*)&qs[0][g][i15][0];
      bf16x8 uh1 = *(const bf16x8*)&qs[0][4 + g][i15][0];
      bf16x8 ul0 = *(const bf16x8*)&qs[1][g][i15][0];
      bf16x8 ul1 = *(const bf16x8*)&qs[1][4 + g][i15][0];
#pragma unroll 2
      for (int js = 0; js < 16; ++js) {
        const size_t kb = (bn * 2048 + (jb + js * 16 + i15)) * 64 + g * 8;
        bf16x8 kh0 = *(const bf16x8*)&Kh[kb];
        bf16x8 kh1 = *(const bf16x8*)&Kh[kb + 32];
        bf16x8 kl0 = *(const bf16x8*)&Kl[kb];
        bf16x8 kl1 = *(const bf16x8*)&Kl[kb + 32];
        f32x4 a = sa[js];
        a = MFB(kh0, uh0, a); a = MFB(kh1, uh1, a);
        a = MFB(kh0, ul0, a); a = MFB(kh1, ul1, a);
        a = MFB(kl0, uh0, a); a = MFB(kl1, uh1, a);
        sa[js] = a;
      }
    }

    // ---- combine shifted D + mask + scale; per-row max
    float m = -1e30f;
#pragma unroll
    for (int js = 0; js < 16; ++js)
#pragma unroll
      for (int r = 0; r < 4; ++r) {
        int j = jb + js * 16 + g * 4 + r;
        float sv = (sa[js][r] + (float)Dl[i15][j + 15 - i15]) * 0.125f;
        sv = (j <= i0 + i15 + 1024) ? sv : -1e30f;
        sa[js][r] = sv;
        m = fmaxf(m, sv);
      }
    m = fmaxf(m, __shfl_xor(m, 16));
    m = fmaxf(m, __shfl_xor(m, 32));
    if (g == 0) red[0][wave][i15] = m;
    __syncthreads();           // (a) combines done -> Dl reusable; maxes in
    float mi = red[0][0][i15];
#pragma unroll
    for (int w = 1; w < 8; ++w) mi = fmaxf(mi, red[0][w][i15]);
    float l = 0.f;
#pragma unroll
    for (int js = 0; js < 16; ++js)
#pragma unroll
      for (int r = 0; r < 4; ++r) {
        float p = __expf(sa[js][r] - mi);
        sa[js][r] = p; l += p;
      }
    l += __shfl_xor(l, 16);
    l += __shfl_xor(l, 32);
    if (g == 0) red[1][wave][i15] = l;
    __syncthreads();           // (b) sums in
    float li = 0.f;
#pragma unroll
    for (int w = 0; w < 8; ++w) li += red[1][w][i15];
    float rinv = 1.f / li;
#pragma unroll
    for (int js = 0; js < 16; ++js) {
      f16x4 pk;
#pragma unroll
      for (int r = 0; r < 4; ++r) pk[r] = (_Float16)(sa[js][r] * rinv);
      *(f16x4*)&Dl[i15][jb + js * 16 + g * 4] = pk;
      pacc[js] += pk;          // head-sum accumulation in registers
    }
    __syncthreads();           // (c) P ready

    // ---- PV: vec_partial = P·V over this wave's slab (f16 MFMA)
    f32x4 va[4];
#pragma unroll
    for (int d = 0; d < 4; ++d) va[d] = (f32x4){};
#pragma unroll 2
    for (int kc = 0; kc < 8; ++kc) {
      f16x8 pa = *(const f16x8*)&Dl[i15][jb + kc * 32 + g * 8];
#pragma unroll
      for (int d = 0; d < 4; ++d) {
        f16x8 vb = *(const f16x8*)&VT[(bn * 64 + d * 16 + i15) * 2048 + jb + kc * 32 + g * 8];
        va[d] = MFH(pa, vb, va[d]);
      }
    }
    __syncthreads();           // (d) all P reads done -> Dl as fp32 scratch
    float* sc2 = (float*)&Dl[0][0];
#pragma unroll
    for (int d = 0; d < 4; ++d)
#pragma unroll
      for (int r = 0; r < 4; ++r)
        sc2[(wave * 16 + g * 4 + r) * 64 + d * 16 + i15] = va[d][r];
    __syncthreads();           // (e) partials staged
    {
      int ii = t >> 5, dp = (t & 31) * 2;
      float s0 = 0.f, s1 = 0.f;
#pragma unroll
      for (int w = 0; w < 8; ++w) {
        s0 += sc2[(w * 16 + ii) * 64 + dp];
        s1 += sc2[(w * 16 + ii) * 64 + dp + 1];
      }
      float* vp = &vec[(((size_t)(i0 + ii) * 4 + b) << 10) + n * 64 + dp];
      vp[0] = s0; vp[1] = s1;
    }
    __syncthreads();           // (f) scratch/qs free for next head
  }

  // ---- write head-summed P once (block-exclusive region, no atomics)
  {
    float* ap = blockIdx.z ? acc1 : acc0;
    float* rp = &ap[((size_t)b * 1024 + i0 + i15) * 2048];
#pragma unroll
    for (int js = 0; js < 16; ++js) {
      float4 o;
      o.x = (float)pacc[js][0]; o.y = (float)pacc[js][1];
      o.z = (float)pacc[js][2]; o.w = (float)pacc[js][3];
      *(float4*)&rp[jb + js * 16 + g * 4] = o;
    }
  }
}

// ---------------- attn matrix finalize: mean over batch + z-halves ----------
__global__ __launch_bounds__(256) void attnfin_k(const float* __restrict__ a0,
                                                 const float* __restrict__ a1,
                                                 float* __restrict__ out)
{
  size_t idx = (size_t)blockIdx.x * 256 + threadIdx.x;
  const size_t S = (size_t)XLEN * TOT;
  float s = 0.f;
#pragma unroll
  for (int b = 0; b < 4; ++b) s += a0[idx + b * S] + a1[idx + b * S];
  out[idx] = s * (1.0f / 64.0f);
}

// ---------------- LayerNorm (+optional bf16 hi/lo split output) -------------
template<int SPLIT>
__global__ __launch_bounds__(256) void ln_k(const float* __restrict__ in,
                                            const float* __restrict__ g,
                                            const float* __restrict__ bb,
                                            float* __restrict__ out,
                                            unsigned short* __restrict__ oh,
                                            unsigned short* __restrict__ ol)
{
  __shared__ float rbuf[8];
  const int row = blockIdx.x;
  const int t = threadIdx.x;
  const float* p = in + (size_t)row * DM;
  float4 v = *(const float4*)(p + t * 4);
  float s1 = v.x + v.y + v.z + v.w;
  float s2 = v.x * v.x + v.y * v.y + v.z * v.z + v.w * v.w;
#pragma unroll
  for (int off = 32; off; off >>= 1) {
    s1 += __shfl_xor(s1, off);
    s2 += __shfl_xor(s2, off);
  }
  const int wv = t >> 6, lane = t & 63;
  if (lane == 0) { rbuf[wv] = s1; rbuf[4 + wv] = s2; }
  __syncthreads();
  if (t == 0) {
    float a = rbuf[0] + rbuf[1] + rbuf[2] + rbuf[3];
    float b2 = rbuf[4] + rbuf[5] + rbuf[6] + rbuf[7];
    float mu = a * (1.f / DM);
    float var = b2 * (1.f / DM) - mu * mu;
    rbuf[0] = mu;
    rbuf[1] = rsqrtf(var + 1e-5f);
  }
  __syncthreads();
  float mu = rbuf[0], rs = rbuf[1];
  float4 gv = *(const float4*)(g + t * 4);
  float4 bv = *(const float4*)(bb + t * 4);
  float4 o;
  o.x = (v.x - mu) * rs * gv.x + bv.x;
  o.y = (v.y - mu) * rs * gv.y + bv.y;
  o.z = (v.z - mu) * rs * gv.z + bv.z;
  o.w = (v.w - mu) * rs * gv.w + bv.w;
  *(float4*)(out + (size_t)row * DM + t * 4) = o;
  if (SPLIT) {
    ushort4 h, l;
    h.x = bf16rn(o.x); l.x = bf16rn(o.x - bf16tof(h.x));
    h.y = bf16rn(o.y); l.y = bf16rn(o.y - bf16tof(h.y));
    h.z = bf16rn(o.z); l.z = bf16rn(o.z - bf16tof(h.z));
    h.w = bf16rn(o.w); l.w = bf16rn(o.w - bf16tof(h.w));
    *(ushort4*)(oh + (size_t)row * DM + t * 4) = h;
    *(ushort4*)(ol + (size_t)row * DM + t * 4) = l;
  }
}

// ---------------- launch ----------------
extern "C" void kernel_launch(void* const* d_in, const int* in_sizes, int n_in,
                              void* d_out, int out_size, void* d_ws, size_t ws_size,
                              hipStream_t stream) {
  const float* x      = (const float*)d_in[0];
  const float* memory = (const float*)d_in[1];
  const float* pos    = (const float*)d_in[2];
  const float* pbu    = (const float*)d_in[3];
  const float* pbv    = (const float*)d_in[4];
  const float* Wq   = (const float*)d_in[6];
  const float* Wkv  = (const float*)d_in[7];
  const float* Wrel = (const float*)d_in[8];
  const float* Wo   = (const float*)d_in[9];
  const float* ln1g = (const float*)d_in[10];
  const float* ln1b = (const float*)d_in[11];
  const float* W1   = (const float*)d_in[12];
  const float* b1   = (const float*)d_in[13];
  const float* W2   = (const float*)d_in[14];
  const float* b2   = (const float*)d_in[15];
  const float* ln2g = (const float*)d_in[16];
  const float* ln2b = (const float*)d_in[17];

  float* out   = (float*)d_out;                    // [1024,4,1024]
  float* attnm = out + (size_t)XLEN * BATCH * DM;  // [1024,2048]
  float* ws = (float*)d_ws;
  const size_t M1 = 1048576;  // 1M floats

  // ---- workspace (offsets in floats; bf16/f16 arrays cast) ----
  unsigned short* c_h   = (unsigned short*)(ws + 0);          // [0,4M)
  unsigned short* c_l   = (unsigned short*)(ws + 4 * M1);     // [4,8M)
  float* pos_f[2] = { ws + 8 * M1, ws + 12 * M1 };            // [8,16M)
  unsigned short* pos_h = (unsigned short*)pos_f[0];
  unsigned short* pos_l = (unsigned short*)pos_f[1];
  unsigned short* Wkvh  = (unsigned short*)(ws + 16 * M1);
  unsigned short* Wkvl  = (unsigned short*)(ws + 17 * M1);
  unsigned short* Wqh   = (unsigned short*)(ws + 18 * M1);
  unsigned short* Wql   = (unsigned short*)(ws + 18 * M1 + M1 / 2);
  unsigned short* Wrelh = (unsigned short*)(ws + 19 * M1);
  unsigned short* Wrell = (unsigned short*)(ws + 19 * M1 + M1 / 2);
  unsigned short* Rh    = (unsigned short*)(ws + 20 * M1);    // [20,24M)
  unsigned short* Rl    = (unsigned short*)(ws + 24 * M1);    // [24,28M)
  unsigned short* Quh   = (unsigned short*)(ws + 28 * M1);    // [28,30M)
  unsigned short* Qul   = (unsigned short*)(ws + 30 * M1);
  unsigned short* Qvh   = (unsigned short*)(ws + 32 * M1);
  unsigned short* Qvl   = (unsigned short*)(ws + 34 * M1);
  unsigned short* Kh    = (unsigned short*)(ws + 8 * M1);     // over pos
  unsigned short* Kl    = (unsigned short*)(ws + 12 * M1);
  unsigned short* VTu   = (unsigned short*)(ws + 36 * M1);    // [36,40M) f16
  float* attnacc0       = ws + 0;                              // over c [0,8M)
  float* attnacc1       = ws + 44 * M1;                        // [44,52M)
  float* vec            = ws + 16 * M1;                        // over W splits
  // post-attention
  unsigned short* vech  = (unsigned short*)(ws + 8 * M1);     // over Kh
  unsigned short* vecl  = (unsigned short*)(ws + 10 * M1);
  unsigned short* W1h   = (unsigned short*)(ws + 12 * M1);    // over Kl
  unsigned short* W1l   = (unsigned short*)(ws + 14 * M1);
  unsigned short* W2h   = (unsigned short*)(ws + 0);          // over attnacc0
  unsigned short* W2l   = (unsigned short*)(ws + 2 * M1);
  unsigned short* Woh   = (unsigned short*)(ws + 4 * M1);
  unsigned short* Wol   = (unsigned short*)(ws + 4 * M1 + M1 / 2);
  float* t1             = ws + 40 * M1;                        // [40,44M)
  float* h              = ws + 16 * M1;                        // over vec
  unsigned short* hhp   = (unsigned short*)(ws + 20 * M1);    // over Rh
  unsigned short* hlp   = (unsigned short*)(ws + 22 * M1);
  unsigned short* ffph  = (unsigned short*)(ws + 24 * M1);    // [24,32M)
  unsigned short* ffpl  = (unsigned short*)(ws + 32 * M1);    // [32,40M)
  float* t2             = ws + 8 * M1;                         // over vech/vecl

  // 1) pre-attention splits
  split2_k<<<8192, 256, 0, stream>>>(memory, x, MEMLEN * BATCH * DM, c_h, c_l);
  split2_k<<<8192, 256, 0, stream>>>(pos, pos, 1 << 30, pos_h, pos_l);
  tsplit_k<<<dim3(16, 32), 256, 0, stream>>>(Wkv, DM, 2048, Wkvh, Wkvl);
  tsplit_k<<<dim3(16, 16), 256, 0, stream>>>(Wq, DM, 1024, Wqh, Wql);
  tsplit_k<<<dim3(16, 16), 256, 0, stream>>>(Wrel, DM, 1024, Wrelh, Wrell);

  // 2) R = pos@Wrel (pos dead after)
  gemm_k<2><<<dim3(8, 64), 256, 0, stream>>>(pos_h, pos_l, Wrelh, Wrell, 1024, DM,
      nullptr, nullptr, nullptr, Rh, Rl, nullptr, nullptr);
  // 3) Qu,Qv = x@Wq (+biases)
  gemm_k<1><<<dim3(8, 32), 256, 0, stream>>>(c_h + 4194304, c_l + 4194304, Wqh, Wql,
      1024, DM, pbu, pbv, nullptr, Quh, Qul, Qvh, Qvl);
  // 4) K,VT = c@Wkv (K overwrites pos region; c dead after)
  gemm_k<0><<<dim3(16, 64), 256, 0, stream>>>(c_h, c_l, Wkvh, Wkvl, 2048, DM,
      nullptr, nullptr, nullptr, Kh, Kl, VTu, nullptr);
  // 5) attention (P head-sums written exclusively; no zeroing needed)
  attn_k<<<dim3(64, 4, 2), 512, 0, stream>>>(Kh, Kl, Rh, Rl, Quh, Qul, Qvh, Qvl,
      (const _Float16*)VTu, vec, attnacc0, attnacc1);
  // 6) attn matrix mean over batch
  attnfin_k<<<(XLEN * TOT) / 256, 256, 0, stream>>>(attnacc0, attnacc1, attnm);

  // 7) post-attention splits
  split2_k<<<4096, 256, 0, stream>>>(vec, vec, 1 << 30, vech, vecl);
  tsplit_k<<<dim3(16, 64), 256, 0, stream>>>(W1, DM, DFF, W1h, W1l);
  tsplit_k<<<dim3(64, 16), 256, 0, stream>>>(W2, DFF, 1024, W2h, W2l);
  tsplit_k<<<dim3(16, 16), 256, 0, stream>>>(Wo, DM, 1024, Woh, Wol);

  // 8) attn_out = vec@Wo + x -> t1
  gemm_k<3><<<dim3(8, 32), 256, 0, stream>>>(vech, vecl, Woh, Wol, 1024, DM,
      x, nullptr, t1, nullptr, nullptr, nullptr, nullptr);
  // 9) h = LN1(t1) + bf16 hi/lo
  ln_k<1><<<XLEN * BATCH, 256, 0, stream>>>(t1, ln1g, ln1b, h, hhp, hlp);
  // 10) ffp = relu(h@W1 + b1) bf16 hi/lo
  gemm_k<4><<<dim3(32, 32), 256, 0, stream>>>(hhp, hlp, W1h, W1l, DFF, DM,
      b1, nullptr, nullptr, ffph, ffpl, nullptr, nullptr);
  // 11) t2 = ffp@W2 + b2 + h
  gemm_k<5><<<dim3(8, 32), 256, 0, stream>>>(ffph, ffpl, W2h, W2l, 1024, DFF,
      b2, h, t2, nullptr, nullptr, nullptr, nullptr);
  // 12) out = LN2(t2)
  ln_k<0><<<XLEN * BATCH, 256, 0, stream>>>(t2, ln2g, ln2b, out, nullptr, nullptr);
}

// Round 9
// 1568.367 us; speedup vs baseline: 4.6754x; 1.1817x over previous
//
#include <hip/hip_runtime.h>

#define NHEAD 16
#define DHEAD 64
#define XLEN 1024
#define MEMLEN 1024
#define BATCH 4
#define TOT 2048
#define DFF 4096
#define DM 1024

typedef __attribute__((ext_vector_type(8))) short bf16x8;
typedef __attribute__((ext_vector_type(4))) float f32x4;
typedef __attribute__((ext_vector_type(8))) _Float16 f16x8;
typedef __attribute__((ext_vector_type(4))) _Float16 f16x4;

#define MFB(A, B, C) __builtin_amdgcn_mfma_f32_16x16x32_bf16(A, B, C, 0, 0, 0)
#define MFH(A, B, C) __builtin_amdgcn_mfma_f32_16x16x32_f16(A, B, C, 0, 0, 0)

__device__ __forceinline__ unsigned short bf16rn(float x) {
  union { float f; unsigned u; } c{x};
  unsigned r = c.u + 0x7fffu + ((c.u >> 16) & 1u);
  return (unsigned short)(r >> 16);
}
__device__ __forceinline__ float bf16tof(unsigned short h) {
  union { unsigned u; float f; } c{(unsigned)h << 16};
  return c.f;
}

#define GLOAD_LDS16(gp, lp)                                                    \
  __builtin_amdgcn_global_load_lds(                                            \
      (const __attribute__((address_space(1))) unsigned int*)(gp),             \
      (__attribute__((address_space(3))) unsigned int*)(lp), 16, 0, 0)

// ---------------- elementwise split: fp32 -> bf16 hi + bf16 lo --------------
__global__ __launch_bounds__(256) void split2_k(
    const float* __restrict__ s0, const float* __restrict__ s1, int splitElems,
    unsigned short* __restrict__ oh, unsigned short* __restrict__ ol)
{
  int i4 = (blockIdx.x * 256 + threadIdx.x) * 4;
  const float* src = (i4 < splitElems) ? (s0 + i4) : (s1 + (i4 - splitElems));
  float4 v = *(const float4*)src;
  ushort4 h, l;
  h.x = bf16rn(v.x); l.x = bf16rn(v.x - bf16tof(h.x));
  h.y = bf16rn(v.y); l.y = bf16rn(v.y - bf16tof(h.y));
  h.z = bf16rn(v.z); l.z = bf16rn(v.z - bf16tof(h.z));
  h.w = bf16rn(v.w); l.w = bf16rn(v.w - bf16tof(h.w));
  *(ushort4*)(oh + i4) = h;
  *(ushort4*)(ol + i4) = l;
}

// ------------- transpose + split: W[K][N] fp32 -> Wt hi/lo [N][K] bf16 ------
__global__ __launch_bounds__(256) void tsplit_k(
    const float* __restrict__ W, int K, int N,
    unsigned short* __restrict__ oh, unsigned short* __restrict__ ol)
{
  __shared__ float tile[64][65];
  const int t = threadIdx.x;
  const int bk = blockIdx.x * 64, bn = blockIdx.y * 64;
#pragma unroll
  for (int r = 0; r < 4; ++r) {
    int lr = r * 16 + (t >> 4), lc = (t & 15) * 4;
    *(float4*)&tile[lr][lc] = *(const float4*)&W[(size_t)(bk + lr) * N + bn + lc];
  }
  __syncthreads();
  const int n = t >> 2, kq = t & 3;
  unsigned short* ph = oh + (size_t)(bn + n) * K + bk + kq * 16;
  unsigned short* pl = ol + (size_t)(bn + n) * K + bk + kq * 16;
#pragma unroll
  for (int c = 0; c < 4; ++c) {
    ushort4 h, l;
    float v0 = tile[kq * 16 + c * 4 + 0][n];
    float v1 = tile[kq * 16 + c * 4 + 1][n];
    float v2 = tile[kq * 16 + c * 4 + 2][n];
    float v3 = tile[kq * 16 + c * 4 + 3][n];
    h.x = bf16rn(v0); l.x = bf16rn(v0 - bf16tof(h.x));
    h.y = bf16rn(v1); l.y = bf16rn(v1 - bf16tof(h.y));
    h.z = bf16rn(v2); l.z = bf16rn(v2 - bf16tof(h.z));
    h.w = bf16rn(v3); l.w = bf16rn(v3 - bf16tof(h.w));
    *(ushort4*)(ph + c * 4) = h;
    *(ushort4*)(pl + c * 4) = l;
  }
}

// ---------------- MFMA GEMM: 128x128 tile, 3-term Markidis ------------------
template<int MODE>
__global__ __launch_bounds__(256) void gemm_k(
    const unsigned short* __restrict__ Ah, const unsigned short* __restrict__ Al,
    const unsigned short* __restrict__ Bh, const unsigned short* __restrict__ Bl,
    int N, int K,
    const float* __restrict__ e0, const float* __restrict__ e1,
    float* __restrict__ o0,
    unsigned short* __restrict__ p0, unsigned short* __restrict__ p1,
    unsigned short* __restrict__ p2, unsigned short* __restrict__ p3)
{
  __shared__ unsigned short lds[4][4096];  // Ah,Al,Bh,Bl: 128 rows x 32 bf16
  const int t = threadIdx.x;
  const int wave = t >> 6, lane = t & 63;
  const int wm = wave >> 1, wn = wave & 1;
  const int m0 = blockIdx.y * 128, n0 = blockIdx.x * 128;

  const unsigned short* gp[2][4];
  unsigned short* lp[2][4];
#pragma unroll
  for (int i = 0; i < 2; ++i) {
    int s = i * 256 + t, row = s >> 2, sl = s & 3;
    int csw = (sl ^ (row & 3)) * 8;
    gp[i][0] = Ah + (size_t)(m0 + row) * K + csw;
    gp[i][1] = Al + (size_t)(m0 + row) * K + csw;
    gp[i][2] = Bh + (size_t)(n0 + row) * K + csw;
    gp[i][3] = Bl + (size_t)(n0 + row) * K + csw;
#pragma unroll
    for (int a = 0; a < 4; ++a) lp[i][a] = &lds[a][s * 8];
  }

  f32x4 acc[4][4] = {};
  const int kg = lane >> 4, r15 = lane & 15;

  for (int k0 = 0; k0 < K; k0 += 32) {
#pragma unroll
    for (int i = 0; i < 2; ++i)
#pragma unroll
      for (int a = 0; a < 4; ++a) GLOAD_LDS16(gp[i][a] + k0, lp[i][a]);
    __syncthreads();

    bf16x8 afh[4], afl[4], bfh[4], bfl[4];
#pragma unroll
    for (int f = 0; f < 4; ++f) {
      int rowA = wm * 64 + f * 16 + r15;
      int ia = (rowA * 4 + (kg ^ (rowA & 3))) * 8;
      afh[f] = *(const bf16x8*)&lds[0][ia];
      afl[f] = *(const bf16x8*)&lds[1][ia];
      int rowB = wn * 64 + f * 16 + r15;
      int ib = (rowB * 4 + (kg ^ (rowB & 3))) * 8;
      bfh[f] = *(const bf16x8*)&lds[2][ib];
      bfl[f] = *(const bf16x8*)&lds[3][ib];
    }
#pragma unroll
    for (int i = 0; i < 4; ++i)
#pragma unroll
      for (int j = 0; j < 4; ++j) {
        acc[i][j] = MFB(afh[i], bfh[j], acc[i][j]);
        acc[i][j] = MFB(afh[i], bfl[j], acc[i][j]);
        acc[i][j] = MFB(afl[i], bfh[j], acc[i][j]);
      }
    __syncthreads();
  }

  // epilogue: C/D layout col = lane&15, row = (lane>>4)*4 + reg
#pragma unroll
  for (int i = 0; i < 4; ++i)
#pragma unroll
    for (int j = 0; j < 4; ++j)
#pragma unroll
      for (int r = 0; r < 4; ++r) {
        int m = m0 + wm * 64 + i * 16 + kg * 4 + r;
        int nn = n0 + wn * 64 + j * 16 + r15;
        float v = acc[i][j][r];
        if (MODE == 0) {           // c@Wkv -> Kh/Kl [B,N,T,64], VT f16 [B,N,64,T]
          int tt = m >> 2, bb = m & 3;
          if (nn < 1024) {
            int hn = nn >> 6, d = nn & 63;
            size_t idx = ((size_t)(bb * 16 + hn) * 2048 + tt) * 64 + d;
            unsigned short hi = bf16rn(v);
            p0[idx] = hi; p1[idx] = bf16rn(v - bf16tof(hi));
          } else {
            int c2 = nn - 1024, hn = c2 >> 6, d = c2 & 63;
            union { _Float16 h; unsigned short u; } cv; cv.h = (_Float16)v;
            p2[((size_t)(bb * 16 + hn) * 64 + d) * 2048 + tt] = cv.u;
          }
        } else if (MODE == 1) {    // x@Wq + biases -> Quh/Qul/Qvh/Qvl [B,N,I,64]
          int i2 = m >> 2, bb = m & 3;
          int hn = nn >> 6, d = nn & 63;
          size_t idx = ((size_t)(bb * 16 + hn) * 1024 + i2) * 64 + d;
          float vu = v + e0[nn], vv = v + e1[nn];
          unsigned short h0 = bf16rn(vu);
          p0[idx] = h0; p1[idx] = bf16rn(vu - bf16tof(h0));
          unsigned short h1 = bf16rn(vv);
          p2[idx] = h1; p3[idx] = bf16rn(vv - bf16tof(h1));
        } else if (MODE == 2) {    // pos@Wrel -> Rh/Rl [B,N,T,64]
          int tt = m >> 2, bb = m & 3;
          int hn = nn >> 6, d = nn & 63;
          size_t idx = ((size_t)(bb * 16 + hn) * 2048 + tt) * 64 + d;
          unsigned short hi = bf16rn(v);
          p0[idx] = hi; p1[idx] = bf16rn(v - bf16tof(hi));
        } else if (MODE == 3) {    // vec@Wo + x -> t1 (fp32)
          o0[(size_t)m * N + nn] = v + e0[(size_t)m * N + nn];
        } else if (MODE == 4) {    // relu(h@W1 + b1) -> ffp hi/lo bf16
          float v2 = fmaxf(v + e0[nn], 0.f);
          unsigned short hh = bf16rn(v2);
          p0[(size_t)m * N + nn] = hh;
          p1[(size_t)m * N + nn] = bf16rn(v2 - bf16tof(hh));
        } else if (MODE == 5) {    // ff@W2 + b2 + h -> t2 (fp32)
          o0[(size_t)m * N + nn] = v + e0[nn] + e1[(size_t)m * N + nn];
        }
      }
}

// ---------------- MFMA attention ----------------
// Round-8 root cause (rule #20): the AC loop was `#pragma unroll 2` with
// sa[js] runtime-indexed -> the whole f32x4 sa[16] array lived in SCRATCH,
// ~2.1 GB/dispatch of spill traffic that no launch-bounds setting could fix
// (VGPR_Count 64/92 were the *non-array* registers). Fix: (a) FULL static
// unrolls everywhere an ext_vector array is indexed; (b) scores never live in
// a register array at all — S goes to a dedicated f16 LDS buffer Sl, softmax
// is a 2-pass LDS sweep, PV consumes unnormalized e with 1/l folded into the
// output staging. Peak live ~100 VGPR -> no spill under any allocator target.
// LDS: Dl 66K + Sl 64K + qs 8K + red/rs ~1.1K = 141 KB -> 1 block/CU.
__global__ __launch_bounds__(512) void attn_k(
    const unsigned short* __restrict__ Kh, const unsigned short* __restrict__ Kl,
    const unsigned short* __restrict__ Rh, const unsigned short* __restrict__ Rl,
    const unsigned short* __restrict__ Quh, const unsigned short* __restrict__ Qul,
    const unsigned short* __restrict__ Qvh, const unsigned short* __restrict__ Qvl,
    const _Float16* __restrict__ VT,
    float* __restrict__ vec, float* __restrict__ acc0, float* __restrict__ acc1)
{
  __shared__ _Float16 Dl[16][2072];            // D window (f16); PV fp32 scratch
  __shared__ _Float16 Sl[16][2048];            // S -> unnormalized e
  __shared__ unsigned short qs[4][8][16][8];   // Q^T frags: arr, dchunk, i, e
  __shared__ float red[2][8][16];
  __shared__ float rs[16];                     // per-row 1/l
  const int t = threadIdx.x, wave = t >> 6, lane = t & 63;
  const int g = lane >> 4, i15 = lane & 15;
  const int i0 = blockIdx.x * 16, b = blockIdx.y;
  const int jr0 = 1008 - i0;
  const int NS = (2048 - jr0) >> 4;
  const int jb = wave * 256;

  f16x4 pacc[16];                              // static-indexed only (rule #20)
#pragma unroll
  for (int js = 0; js < 16; ++js) pacc[js] = (f16x4){};

  for (int hh = 0; hh < 8; ++hh) {
    const int n = blockIdx.z * 8 + hh;
    const size_t bn = (size_t)(b * 16 + n);

    {  // stage Q^T tiles (transpose into frag-ready layout)
      int a = t & 127, arr = t >> 7;
      const unsigned short* sp = arr == 0 ? Quh : arr == 1 ? Qul
                               : arr == 2 ? Qvh : Qvl;
      *(uint4*)&qs[arr][a >> 4][a & 15][0] =
          *(const uint4*)&sp[((bn << 10) + i0 + (a & 15)) * 64 + (a >> 4) * 8];
    }
    __syncthreads();

    // ---- D^T phase: D[jr][i] = R[jr]·Qv[i], subtiles round-robin over waves
    for (int s = wave; s < NS; s += 8) {
      const size_t kb = (bn * 2048 + (jr0 + s * 16 + i15)) * 64 + g * 8;
      bf16x8 rh0 = *(const bf16x8*)&Rh[kb];
      bf16x8 rh1 = *(const bf16x8*)&Rh[kb + 32];
      bf16x8 rl0 = *(const bf16x8*)&Rl[kb];
      bf16x8 rl1 = *(const bf16x8*)&Rl[kb + 32];
      bf16x8 vh0 = *(const bf16x8*)&qs[2][g][i15][0];
      bf16x8 vh1 = *(const bf16x8*)&qs[2][4 + g][i15][0];
      bf16x8 vl0 = *(const bf16x8*)&qs[3][g][i15][0];
      bf16x8 vl1 = *(const bf16x8*)&qs[3][4 + g][i15][0];
      f32x4 dacc = {};
      dacc = MFB(rh0, vh0, dacc); dacc = MFB(rh1, vh1, dacc);
      dacc = MFB(rh0, vl0, dacc); dacc = MFB(rh1, vl1, dacc);
      dacc = MFB(rl0, vh0, dacc); dacc = MFB(rl1, vh1, dacc);
#pragma unroll
      for (int r = 0; r < 4; ++r)
        Dl[i15][s * 16 + g * 4 + r] = (_Float16)dacc[r];
    }
    __syncthreads();

    // ---- AC phase: S^T = K·Qu, combine D, mask, scale -> Sl (f16); track max
    float m = -1e30f;
    {
      bf16x8 uh0 = *(const bf16x8*)&qs[0][g][i15][0];
      bf16x8 uh1 = *(const bf16x8*)&qs[0][4 + g][i15][0];
      bf16x8 ul0 = *(const bf16x8*)&qs[1][g][i15][0];
      bf16x8 ul1 = *(const bf16x8*)&qs[1][4 + g][i15][0];
#pragma unroll
      for (int js = 0; js < 16; ++js) {         // FULL unroll (rule #20)
        const size_t kb = (bn * 2048 + (jb + js * 16 + i15)) * 64 + g * 8;
        bf16x8 kh0 = *(const bf16x8*)&Kh[kb];
        bf16x8 kh1 = *(const bf16x8*)&Kh[kb + 32];
        bf16x8 kl0 = *(const bf16x8*)&Kl[kb];
        bf16x8 kl1 = *(const bf16x8*)&Kl[kb + 32];
        f32x4 a = {};
        a = MFB(kh0, uh0, a); a = MFB(kh1, uh1, a);
        a = MFB(kh0, ul0, a); a = MFB(kh1, ul1, a);
        a = MFB(kl0, uh0, a); a = MFB(kl1, uh1, a);
        f16x4 s4;
#pragma unroll
        for (int r = 0; r < 4; ++r) {
          int j = jb + js * 16 + g * 4 + r;
          float sv = (a[r] + (float)Dl[i15][j + 15 - i15]) * 0.125f;
          sv = (j <= i0 + i15 + 1024) ? sv : -1e30f;
          s4[r] = (_Float16)sv;                 // masked -> f16 -inf
          m = fmaxf(m, sv);
        }
        *(f16x4*)&Sl[i15][jb + js * 16 + g * 4] = s4;
      }
    }
    m = fmaxf(m, __shfl_xor(m, 16));
    m = fmaxf(m, __shfl_xor(m, 32));
    if (g == 0) red[0][wave][i15] = m;
    __syncthreads();           // (a) maxes in; Sl writes done (own slab)
    float mi = red[0][0][i15];
#pragma unroll
    for (int w = 1; w < 8; ++w) mi = fmaxf(mi, red[0][w][i15]);

    // ---- pass B: e = exp(S - mi) -> Sl (unnormalized); row-sum l
    float l = 0.f;
#pragma unroll
    for (int js = 0; js < 16; ++js) {
      f16x4 s4 = *(const f16x4*)&Sl[i15][jb + js * 16 + g * 4];
      f16x4 e4;
#pragma unroll
      for (int r = 0; r < 4; ++r) {
        float e = __expf((float)s4[r] - mi);
        e4[r] = (_Float16)e;
        l += e;
      }
      *(f16x4*)&Sl[i15][jb + js * 16 + g * 4] = e4;
    }
    l += __shfl_xor(l, 16);
    l += __shfl_xor(l, 32);
    if (g == 0) red[1][wave][i15] = l;
    __syncthreads();           // (b) sums in
    float li = 0.f;
#pragma unroll
    for (int w = 0; w < 8; ++w) li += red[1][w][i15];
    float rinv = 1.f / li;
    if (wave == 0 && g == 0) rs[i15] = rinv;

    // ---- pass C: pacc += e * rinv (P head-sum, own slab, f16 accumulate)
#pragma unroll
    for (int js = 0; js < 16; ++js) {
      f16x4 e4 = *(const f16x4*)&Sl[i15][jb + js * 16 + g * 4];
#pragma unroll
      for (int r = 0; r < 4; ++r)
        pacc[js][r] += (_Float16)((float)e4[r] * rinv);
    }

    // ---- PV: va = e·V over this wave's slab (f16 MFMA); FULL unroll
    f32x4 va[4];
#pragma unroll
    for (int d = 0; d < 4; ++d) va[d] = (f32x4){};
#pragma unroll
    for (int kc = 0; kc < 8; ++kc) {
      f16x8 pa = *(const f16x8*)&Sl[i15][jb + kc * 32 + g * 8];
#pragma unroll
      for (int d = 0; d < 4; ++d) {
        f16x8 vb = *(const f16x8*)&VT[(bn * 64 + d * 16 + i15) * 2048 + jb + kc * 32 + g * 8];
        va[d] = MFH(pa, vb, va[d]);
      }
    }
    __syncthreads();           // (d) Dl reads done; rs visible -> Dl as scratch
    float* sc2 = (float*)&Dl[0][0];
#pragma unroll
    for (int d = 0; d < 4; ++d)
#pragma unroll
      for (int r = 0; r < 4; ++r)
        sc2[(wave * 16 + g * 4 + r) * 64 + d * 16 + i15] = va[d][r] * rs[g * 4 + r];
    __syncthreads();           // (e) partials staged
    {
      int ii = t >> 5, dp = (t & 31) * 2;
      float s0 = 0.f, s1 = 0.f;
#pragma unroll
      for (int w = 0; w < 8; ++w) {
        s0 += sc2[(w * 16 + ii) * 64 + dp];
        s1 += sc2[(w * 16 + ii) * 64 + dp + 1];
      }
      float* vp = &vec[(((size_t)(i0 + ii) * 4 + b) << 10) + n * 64 + dp];
      vp[0] = s0; vp[1] = s1;
    }
    __syncthreads();           // (f) scratch/qs/Sl free for next head
  }

  // ---- write head-summed P once (block-exclusive region, no atomics)
  {
    float* ap = blockIdx.z ? acc1 : acc0;
    float* rp = &ap[((size_t)b * 1024 + i0 + i15) * 2048];
#pragma unroll
    for (int js = 0; js < 16; ++js) {
      float4 o;
      o.x = (float)pacc[js][0]; o.y = (float)pacc[js][1];
      o.z = (float)pacc[js][2]; o.w = (float)pacc[js][3];
      *(float4*)&rp[jb + js * 16 + g * 4] = o;
    }
  }
}

// ---------------- attn matrix finalize: mean over batch + z-halves ----------
__global__ __launch_bounds__(256) void attnfin_k(const float* __restrict__ a0,
                                                 const float* __restrict__ a1,
                                                 float* __restrict__ out)
{
  size_t idx = (size_t)blockIdx.x * 256 + threadIdx.x;
  const size_t S = (size_t)XLEN * TOT;
  float s = 0.f;
#pragma unroll
  for (int b = 0; b < 4; ++b) s += a0[idx + b * S] + a1[idx + b * S];
  out[idx] = s * (1.0f / 64.0f);
}

// ---------------- LayerNorm (+optional bf16 hi/lo split output) -------------
template<int SPLIT>
__global__ __launch_bounds__(256) void ln_k(const float* __restrict__ in,
                                            const float* __restrict__ g,
                                            const float* __restrict__ bb,
                                            float* __restrict__ out,
                                            unsigned short* __restrict__ oh,
                                            unsigned short* __restrict__ ol)
{
  __shared__ float rbuf[8];
  const int row = blockIdx.x;
  const int t = threadIdx.x;
  const float* p = in + (size_t)row * DM;
  float4 v = *(const float4*)(p + t * 4);
  float s1 = v.x + v.y + v.z + v.w;
  float s2 = v.x * v.x + v.y * v.y + v.z * v.z + v.w * v.w;
#pragma unroll
  for (int off = 32; off; off >>= 1) {
    s1 += __shfl_xor(s1, off);
    s2 += __shfl_xor(s2, off);
  }
  const int wv = t >> 6, lane = t & 63;
  if (lane == 0) { rbuf[wv] = s1; rbuf[4 + wv] = s2; }
  __syncthreads();
  if (t == 0) {
    float a = rbuf[0] + rbuf[1] + rbuf[2] + rbuf[3];
    float b2 = rbuf[4] + rbuf[5] + rbuf[6] + rbuf[7];
    float mu = a * (1.f / DM);
    float var = b2 * (1.f / DM) - mu * mu;
    rbuf[0] = mu;
    rbuf[1] = rsqrtf(var + 1e-5f);
  }
  __syncthreads();
  float mu = rbuf[0], rs = rbuf[1];
  float4 gv = *(const float4*)(g + t * 4);
  float4 bv = *(const float4*)(bb + t * 4);
  float4 o;
  o.x = (v.x - mu) * rs * gv.x + bv.x;
  o.y = (v.y - mu) * rs * gv.y + bv.y;
  o.z = (v.z - mu) * rs * gv.z + bv.z;
  o.w = (v.w - mu) * rs * gv.w + bv.w;
  *(float4*)(out + (size_t)row * DM + t * 4) = o;
  if (SPLIT) {
    ushort4 h, l;
    h.x = bf16rn(o.x); l.x = bf16rn(o.x - bf16tof(h.x));
    h.y = bf16rn(o.y); l.y = bf16rn(o.y - bf16tof(h.y));
    h.z = bf16rn(o.z); l.z = bf16rn(o.z - bf16tof(h.z));
    h.w = bf16rn(o.w); l.w = bf16rn(o.w - bf16tof(h.w));
    *(ushort4*)(oh + (size_t)row * DM + t * 4) = h;
    *(ushort4*)(ol + (size_t)row * DM + t * 4) = l;
  }
}

// ---------------- launch ----------------
extern "C" void kernel_launch(void* const* d_in, const int* in_sizes, int n_in,
                              void* d_out, int out_size, void* d_ws, size_t ws_size,
                              hipStream_t stream) {
  const float* x      = (const float*)d_in[0];
  const float* memory = (const float*)d_in[1];
  const float* pos    = (const float*)d_in[2];
  const float* pbu    = (const float*)d_in[3];
  const float* pbv    = (const float*)d_in[4];
  const float* Wq   = (const float*)d_in[6];
  const float* Wkv  = (const float*)d_in[7];
  const float* Wrel = (const float*)d_in[8];
  const float* Wo   = (const float*)d_in[9];
  const float* ln1g = (const float*)d_in[10];
  const float* ln1b = (const float*)d_in[11];
  const float* W1   = (const float*)d_in[12];
  const float* b1   = (const float*)d_in[13];
  const float* W2   = (const float*)d_in[14];
  const float* b2   = (const float*)d_in[15];
  const float* ln2g = (const float*)d_in[16];
  const float* ln2b = (const float*)d_in[17];

  float* out   = (float*)d_out;                    // [1024,4,1024]
  float* attnm = out + (size_t)XLEN * BATCH * DM;  // [1024,2048]
  float* ws = (float*)d_ws;
  const size_t M1 = 1048576;  // 1M floats

  // ---- workspace (offsets in floats; bf16/f16 arrays cast) ----
  unsigned short* c_h   = (unsigned short*)(ws + 0);          // [0,4M)
  unsigned short* c_l   = (unsigned short*)(ws + 4 * M1);     // [4,8M)
  float* pos_f[2] = { ws + 8 * M1, ws + 12 * M1 };            // [8,16M)
  unsigned short* pos_h = (unsigned short*)pos_f[0];
  unsigned short* pos_l = (unsigned short*)pos_f[1];
  unsigned short* Wkvh  = (unsigned short*)(ws + 16 * M1);
  unsigned short* Wkvl  = (unsigned short*)(ws + 17 * M1);
  unsigned short* Wqh   = (unsigned short*)(ws + 18 * M1);
  unsigned short* Wql   = (unsigned short*)(ws + 18 * M1 + M1 / 2);
  unsigned short* Wrelh = (unsigned short*)(ws + 19 * M1);
  unsigned short* Wrell = (unsigned short*)(ws + 19 * M1 + M1 / 2);
  unsigned short* Rh    = (unsigned short*)(ws + 20 * M1);    // [20,24M)
  unsigned short* Rl    = (unsigned short*)(ws + 24 * M1);    // [24,28M)
  unsigned short* Quh   = (unsigned short*)(ws + 28 * M1);    // [28,30M)
  unsigned short* Qul   = (unsigned short*)(ws + 30 * M1);
  unsigned short* Qvh   = (unsigned short*)(ws + 32 * M1);
  unsigned short* Qvl   = (unsigned short*)(ws + 34 * M1);
  unsigned short* Kh    = (unsigned short*)(ws + 8 * M1);     // over pos
  unsigned short* Kl    = (unsigned short*)(ws + 12 * M1);
  unsigned short* VTu   = (unsigned short*)(ws + 36 * M1);    // [36,40M) f16
  float* attnacc0       = ws + 0;                              // over c [0,8M)
  float* attnacc1       = ws + 44 * M1;                        // [44,52M)
  float* vec            = ws + 16 * M1;                        // over W splits
  // post-attention
  unsigned short* vech  = (unsigned short*)(ws + 8 * M1);     // over Kh
  unsigned short* vecl  = (unsigned short*)(ws + 10 * M1);
  unsigned short* W1h   = (unsigned short*)(ws + 12 * M1);    // over Kl
  unsigned short* W1l   = (unsigned short*)(ws + 14 * M1);
  unsigned short* W2h   = (unsigned short*)(ws + 0);          // over attnacc0
  unsigned short* W2l   = (unsigned short*)(ws + 2 * M1);
  unsigned short* Woh   = (unsigned short*)(ws + 4 * M1);
  unsigned short* Wol   = (unsigned short*)(ws + 4 * M1 + M1 / 2);
  float* t1             = ws + 40 * M1;                        // [40,44M)
  float* h              = ws + 16 * M1;                        // over vec
  unsigned short* hhp   = (unsigned short*)(ws + 20 * M1);    // over Rh
  unsigned short* hlp   = (unsigned short*)(ws + 22 * M1);
  unsigned short* ffph  = (unsigned short*)(ws + 24 * M1);    // [24,32M)
  unsigned short* ffpl  = (unsigned short*)(ws + 32 * M1);    // [32,40M)
  float* t2             = ws + 8 * M1;                         // over vech/vecl

  // 1) pre-attention splits
  split2_k<<<8192, 256, 0, stream>>>(memory, x, MEMLEN * BATCH * DM, c_h, c_l);
  split2_k<<<8192, 256, 0, stream>>>(pos, pos, 1 << 30, pos_h, pos_l);
  tsplit_k<<<dim3(16, 32), 256, 0, stream>>>(Wkv, DM, 2048, Wkvh, Wkvl);
  tsplit_k<<<dim3(16, 16), 256, 0, stream>>>(Wq, DM, 1024, Wqh, Wql);
  tsplit_k<<<dim3(16, 16), 256, 0, stream>>>(Wrel, DM, 1024, Wrelh, Wrell);

  // 2) R = pos@Wrel (pos dead after)
  gemm_k<2><<<dim3(8, 64), 256, 0, stream>>>(pos_h, pos_l, Wrelh, Wrell, 1024, DM,
      nullptr, nullptr, nullptr, Rh, Rl, nullptr, nullptr);
  // 3) Qu,Qv = x@Wq (+biases)
  gemm_k<1><<<dim3(8, 32), 256, 0, stream>>>(c_h + 4194304, c_l + 4194304, Wqh, Wql,
      1024, DM, pbu, pbv, nullptr, Quh, Qul, Qvh, Qvl);
  // 4) K,VT = c@Wkv (K overwrites pos region; c dead after)
  gemm_k<0><<<dim3(16, 64), 256, 0, stream>>>(c_h, c_l, Wkvh, Wkvl, 2048, DM,
      nullptr, nullptr, nullptr, Kh, Kl, VTu, nullptr);
  // 5) attention (P head-sums written exclusively; no zeroing needed)
  attn_k<<<dim3(64, 4, 2), 512, 0, stream>>>(Kh, Kl, Rh, Rl, Quh, Qul, Qvh, Qvl,
      (const _Float16*)VTu, vec, attnacc0, attnacc1);
  // 6) attn matrix mean over batch
  attnfin_k<<<(XLEN * TOT) / 256, 256, 0, stream>>>(attnacc0, attnacc1, attnm);

  // 7) post-attention splits
  split2_k<<<4096, 256, 0, stream>>>(vec, vec, 1 << 30, vech, vecl);
  tsplit_k<<<dim3(16, 64), 256, 0, stream>>>(W1, DM, DFF, W1h, W1l);
  tsplit_k<<<dim3(64, 16), 256, 0, stream>>>(W2, DFF, 1024, W2h, W2l);
  tsplit_k<<<dim3(16, 16), 256, 0, stream>>>(Wo, DM, 1024, Woh, Wol);

  // 8) attn_out = vec@Wo + x -> t1
  gemm_k<3><<<dim3(8, 32), 256, 0, stream>>>(vech, vecl, Woh, Wol, 1024, DM,
      x, nullptr, t1, nullptr, nullptr, nullptr, nullptr);
  // 9) h = LN1(t1) + bf16 hi/lo
  ln_k<1><<<XLEN * BATCH, 256, 0, stream>>>(t1, ln1g, ln1b, h, hhp, hlp);
  // 10) ffp = relu(h@W1 + b1) bf16 hi/lo
  gemm_k<4><<<dim3(32, 32), 256, 0, stream>>>(hhp, hlp, W1h, W1l, DFF, DM,
      b1, nullptr, nullptr, ffph, ffpl, nullptr, nullptr);
  // 11) t2 = ffp@W2 + b2 + h
  gemm_k<5><<<dim3(8, 32), 256, 0, stream>>>(ffph, ffpl, W2h, W2l, 1024, DFF,
      b2, h, t2, nullptr, nullptr, nullptr, nullptr);
  // 12) out = LN2(t2)
  ln_k<0><<<XLEN * BATCH, 256, 0, stream>>>(t2, ln2g, ln2b, out, nullptr, nullptr);
}